// Round 2
// baseline (3307.135 us; speedup 1.0000x reference)
//
#include <hip/hip_runtime.h>
#include <math.h>

#define NH      16
#define D_NOPE  128
#define D_ROPE  64
#define D_QK    192
#define D_V     128
#define KV_LORA 512
#define NB      2
#define SEQ     2048
#define NTOK    (NB*SEQ)          // 4096
#define QROW    (NH*D_QK)         // 3072
#define KVBROW  (NH*(D_NOPE+D_V)) // 4096
#define EPSF    1e-6f

// ---------------------------------------------------------------------------
// Tiled NT GEMM: C[M,N] = A[M,K] @ B[N,K]^T ; M,N mult of 64, K mult of 16.
// ---------------------------------------------------------------------------
__global__ __launch_bounds__(256) void gemm_nt(const float* __restrict__ A,
                                               const float* __restrict__ B,
                                               float* __restrict__ C,
                                               int M, int N, int K) {
    __shared__ float As[16][64];
    __shared__ float Bs[16][64];
    const int tid = threadIdx.x;
    const int tx = tid & 15, ty = tid >> 4;
    const int m0 = blockIdx.y * 64, n0 = blockIdx.x * 64;
    const int lr = tid >> 2;          // 0..63
    const int lc = (tid & 3) * 4;     // 0,4,8,12
    float acc[4][4] = {};
    for (int k0 = 0; k0 < K; k0 += 16) {
        const float4 av = *(const float4*)&A[(size_t)(m0 + lr) * K + k0 + lc];
        const float4 bv = *(const float4*)&B[(size_t)(n0 + lr) * K + k0 + lc];
        __syncthreads();
        As[lc+0][lr] = av.x; As[lc+1][lr] = av.y; As[lc+2][lr] = av.z; As[lc+3][lr] = av.w;
        Bs[lc+0][lr] = bv.x; Bs[lc+1][lr] = bv.y; Bs[lc+2][lr] = bv.z; Bs[lc+3][lr] = bv.w;
        __syncthreads();
#pragma unroll
        for (int k = 0; k < 16; ++k) {
            const float4 a = *(const float4*)&As[k][ty * 4];
            const float4 b = *(const float4*)&Bs[k][tx * 4];
            acc[0][0] += a.x*b.x; acc[0][1] += a.x*b.y; acc[0][2] += a.x*b.z; acc[0][3] += a.x*b.w;
            acc[1][0] += a.y*b.x; acc[1][1] += a.y*b.y; acc[1][2] += a.y*b.z; acc[1][3] += a.y*b.w;
            acc[2][0] += a.z*b.x; acc[2][1] += a.z*b.y; acc[2][2] += a.z*b.z; acc[2][3] += a.z*b.w;
            acc[3][0] += a.w*b.x; acc[3][1] += a.w*b.y; acc[3][2] += a.w*b.z; acc[3][3] += a.w*b.w;
        }
    }
#pragma unroll
    for (int i = 0; i < 4; ++i) {
        float4 o = make_float4(acc[i][0], acc[i][1], acc[i][2], acc[i][3]);
        *(float4*)&C[(size_t)(m0 + ty * 4 + i) * N + n0 + tx * 4] = o;
    }
}

// NOTE: the reference computes q_pe = rotary(q_pe) but then uses the ORIGINAL
// (unrotated) q in the score einsum — the rotated q_pe is dead code in the
// reference. So we must NOT apply RoPE to q. Only k_pe is rotated.

// ---------------------------------------------------------------------------
// Per-token: rmsnorm(kv_c)*w -> kvn[512]; rotary(k_pe) -> kpe[64].
// One 256-thread block per token row.
// ---------------------------------------------------------------------------
__global__ __launch_bounds__(256) void kv_fix(const float* __restrict__ kv_raw,
                                              const float* __restrict__ w,
                                              const float* __restrict__ fcos,
                                              const float* __restrict__ fsin,
                                              float* __restrict__ kvn,
                                              float* __restrict__ kpe) {
    const int row = blockIdx.x;
    const int tid = threadIdx.x;
    const float* src = kv_raw + (size_t)row * (KV_LORA + D_ROPE);
    const float v0 = src[tid];
    const float v1 = src[256 + tid];
    float ss = v0 * v0 + v1 * v1;
#pragma unroll
    for (int off = 32; off > 0; off >>= 1) ss += __shfl_down(ss, off, 64);
    __shared__ float red[4];
    if ((tid & 63) == 0) red[tid >> 6] = ss;
    __syncthreads();
    const float tot = red[0] + red[1] + red[2] + red[3];
    const float inv = rsqrtf(tot * (1.0f / KV_LORA) + EPSF);
    kvn[(size_t)row * KV_LORA + tid]       = v0 * inv * w[tid];
    kvn[(size_t)row * KV_LORA + 256 + tid] = v1 * inv * w[256 + tid];
    if (tid < 32) {
        const int s = row & (SEQ - 1);
        const float c  = fcos[s * 32 + tid];
        const float sn = fsin[s * 32 + tid];
        const float xr = src[KV_LORA + 2 * tid];
        const float xi = src[KV_LORA + 2 * tid + 1];
        kpe[(size_t)row * D_ROPE + 2 * tid]     = xr * c - xi * sn;
        kpe[(size_t)row * D_ROPE + 2 * tid + 1] = xr * sn + xi * c;
    }
}

// ---------------------------------------------------------------------------
// Causal flash attention, fp32. Block = 256 thr = one (b,h,64-row q-tile).
// LDS union: score phase {Qs[64][68]@0, Ks[64][68]@4352}, PV phase
// {Ps[64][68]@0, Vs[64][128]@4352}. 50 KB.
// ---------------------------------------------------------------------------
__global__ __launch_bounds__(256) void attn_kernel(const float* __restrict__ qbuf,
                                                   const float* __restrict__ kvb,
                                                   const float* __restrict__ kpe,
                                                   float* __restrict__ att,
                                                   float scale) {
    __shared__ float smem[12544];
    const int qt = blockIdx.x, h = blockIdx.y, b = blockIdx.z;
    const int tid = threadIdx.x;
    const int tx = tid & 15, ty = tid >> 4;
    const int row0 = b * SEQ + qt * 64;

    float oacc[4][8];
#pragma unroll
    for (int i = 0; i < 4; ++i)
#pragma unroll
        for (int j = 0; j < 8; ++j) oacc[i][j] = 0.f;
    float mrow[4], lrow[4];
#pragma unroll
    for (int i = 0; i < 4; ++i) { mrow[i] = -1e30f; lrow[i] = 0.f; }

    for (int tt = 0; tt <= qt; ++tt) {
        const int t0 = tt * 64;
        float sacc[4][4] = {};
        // ---- score: S = Q(64x192) @ K^T, in 3 chunks of 64 dims ----
        for (int dc = 0; dc < 3; ++dc) {
            __syncthreads();   // previous users of the region are done
            const int dl = (tid & 15) * 4;
#pragma unroll
            for (int mi = 0; mi < 4; ++mi) {
                const int m = (tid >> 4) + 16 * mi;
                const float4 qv = *(const float4*)&qbuf[(size_t)(row0 + m) * QROW + h * D_QK + dc * 64 + dl];
                smem[(dl+0)*68 + m] = qv.x; smem[(dl+1)*68 + m] = qv.y;
                smem[(dl+2)*68 + m] = qv.z; smem[(dl+3)*68 + m] = qv.w;
                const float4 kv = (dc < 2)
                    ? *(const float4*)&kvb[(size_t)(b * SEQ + t0 + m) * KVBROW + h * 256 + dc * 64 + dl]
                    : *(const float4*)&kpe[(size_t)(b * SEQ + t0 + m) * D_ROPE + dl];
                smem[4352 + (dl+0)*68 + m] = kv.x; smem[4352 + (dl+1)*68 + m] = kv.y;
                smem[4352 + (dl+2)*68 + m] = kv.z; smem[4352 + (dl+3)*68 + m] = kv.w;
            }
            __syncthreads();
#pragma unroll 8
            for (int k = 0; k < 64; ++k) {
                const float4 a = *(const float4*)&smem[k * 68 + ty * 4];
                const float4 bb = *(const float4*)&smem[4352 + k * 68 + tx * 4];
                sacc[0][0] += a.x*bb.x; sacc[0][1] += a.x*bb.y; sacc[0][2] += a.x*bb.z; sacc[0][3] += a.x*bb.w;
                sacc[1][0] += a.y*bb.x; sacc[1][1] += a.y*bb.y; sacc[1][2] += a.y*bb.z; sacc[1][3] += a.y*bb.w;
                sacc[2][0] += a.z*bb.x; sacc[2][1] += a.z*bb.y; sacc[2][2] += a.z*bb.z; sacc[2][3] += a.z*bb.w;
                sacc[3][0] += a.w*bb.x; sacc[3][1] += a.w*bb.y; sacc[3][2] += a.w*bb.z; sacc[3][3] += a.w*bb.w;
            }
        }
        // ---- online softmax (registers + 16-lane shuffles) ----
        float p[4][4];
#pragma unroll
        for (int i = 0; i < 4; ++i) {
            const int srow = qt * 64 + ty * 4 + i;
            float sv[4];
#pragma unroll
            for (int j = 0; j < 4; ++j) {
                const int tcol = t0 + tx * 4 + j;
                sv[j] = (tcol <= srow) ? sacc[i][j] * scale : -1e30f;
            }
            float rmax = fmaxf(fmaxf(sv[0], sv[1]), fmaxf(sv[2], sv[3]));
            rmax = fmaxf(rmax, __shfl_xor(rmax, 1));
            rmax = fmaxf(rmax, __shfl_xor(rmax, 2));
            rmax = fmaxf(rmax, __shfl_xor(rmax, 4));
            rmax = fmaxf(rmax, __shfl_xor(rmax, 8));
            const float mnew = fmaxf(mrow[i], rmax);
            const float alpha = __expf(mrow[i] - mnew);
            mrow[i] = mnew;
            float rsum = 0.f;
#pragma unroll
            for (int j = 0; j < 4; ++j) { p[i][j] = __expf(sv[j] - mnew); rsum += p[i][j]; }
            rsum += __shfl_xor(rsum, 1);
            rsum += __shfl_xor(rsum, 2);
            rsum += __shfl_xor(rsum, 4);
            rsum += __shfl_xor(rsum, 8);
            lrow[i] = lrow[i] * alpha + rsum;
#pragma unroll
            for (int j = 0; j < 8; ++j) oacc[i][j] *= alpha;
        }
        __syncthreads();   // all waves done reading Q/K regions
        // ---- write P^T[t'][m], stage V[t'][dv] ----
#pragma unroll
        for (int j = 0; j < 4; ++j) {
            float4 pc = make_float4(p[0][j], p[1][j], p[2][j], p[3][j]);
            *(float4*)&smem[(tx * 4 + j) * 68 + ty * 4] = pc;
        }
        {
            const int dv = (tid & 31) * 4;
            const int tb = tid >> 5;
#pragma unroll
            for (int vi = 0; vi < 8; ++vi) {
                const int tp = tb + 8 * vi;
                const float4 vv = *(const float4*)&kvb[(size_t)(b * SEQ + t0 + tp) * KVBROW + h * 256 + D_NOPE + dv];
                *(float4*)&smem[4352 + tp * 128 + dv] = vv;
            }
        }
        __syncthreads();
        // ---- O += P @ V ----
#pragma unroll 8
        for (int k = 0; k < 64; ++k) {
            const float4 pv = *(const float4*)&smem[k * 68 + ty * 4];
            const float4 v0 = *(const float4*)&smem[4352 + k * 128 + tx * 8];
            const float4 v1 = *(const float4*)&smem[4352 + k * 128 + tx * 8 + 4];
            oacc[0][0] += pv.x*v0.x; oacc[0][1] += pv.x*v0.y; oacc[0][2] += pv.x*v0.z; oacc[0][3] += pv.x*v0.w;
            oacc[0][4] += pv.x*v1.x; oacc[0][5] += pv.x*v1.y; oacc[0][6] += pv.x*v1.z; oacc[0][7] += pv.x*v1.w;
            oacc[1][0] += pv.y*v0.x; oacc[1][1] += pv.y*v0.y; oacc[1][2] += pv.y*v0.z; oacc[1][3] += pv.y*v0.w;
            oacc[1][4] += pv.y*v1.x; oacc[1][5] += pv.y*v1.y; oacc[1][6] += pv.y*v1.z; oacc[1][7] += pv.y*v1.w;
            oacc[2][0] += pv.z*v0.x; oacc[2][1] += pv.z*v0.y; oacc[2][2] += pv.z*v0.z; oacc[2][3] += pv.z*v0.w;
            oacc[2][4] += pv.z*v1.x; oacc[2][5] += pv.z*v1.y; oacc[2][6] += pv.z*v1.z; oacc[2][7] += pv.z*v1.w;
            oacc[3][0] += pv.w*v0.x; oacc[3][1] += pv.w*v0.y; oacc[3][2] += pv.w*v0.z; oacc[3][3] += pv.w*v0.w;
            oacc[3][4] += pv.w*v1.x; oacc[3][5] += pv.w*v1.y; oacc[3][6] += pv.w*v1.z; oacc[3][7] += pv.w*v1.w;
        }
    }
    // ---- epilogue: O /= l, store ----
#pragma unroll
    for (int i = 0; i < 4; ++i) {
        const float inv = 1.0f / lrow[i];
        float4 o0 = make_float4(oacc[i][0]*inv, oacc[i][1]*inv, oacc[i][2]*inv, oacc[i][3]*inv);
        float4 o1 = make_float4(oacc[i][4]*inv, oacc[i][5]*inv, oacc[i][6]*inv, oacc[i][7]*inv);
        float* dst = att + (size_t)(row0 + ty * 4 + i) * (NH * D_V) + h * D_V + tx * 8;
        *(float4*)dst = o0;
        *(float4*)(dst + 4) = o1;
    }
}

// ---------------------------------------------------------------------------
extern "C" void kernel_launch(void* const* d_in, const int* in_sizes, int n_in,
                              void* d_out, int out_size, void* d_ws, size_t ws_size,
                              hipStream_t stream) {
    const float* x     = (const float*)d_in[0];
    const float* wq    = (const float*)d_in[1];
    const float* wkv_a = (const float*)d_in[2];
    const float* knw   = (const float*)d_in[3];
    const float* wkv_b = (const float*)d_in[4];
    const float* wo    = (const float*)d_in[5];
    const float* fcos  = (const float*)d_in[6];
    const float* fsin  = (const float*)d_in[7];
    float* out = (float*)d_out;

    float* q_buf  = (float*)d_ws;                       // 4096*3072
    float* kv_raw = q_buf  + (size_t)NTOK * QROW;       // 4096*576
    float* kvn    = kv_raw + (size_t)NTOK * (KV_LORA + D_ROPE);  // 4096*512
    float* kpe    = kvn    + (size_t)NTOK * KV_LORA;    // 4096*64
    float* kvb    = kpe    + (size_t)NTOK * D_ROPE;     // 4096*4096
    float* att    = kvb    + (size_t)NTOK * KVBROW;     // 4096*2048

    const double mm = 0.1 * 1.0 * log(40.0) + 1.0;
    const float scale = (float)((1.0 / sqrt((double)D_QK)) * mm * mm);

    dim3 blk(256);
    gemm_nt<<<dim3(QROW / 64, NTOK / 64), blk, 0, stream>>>(x, wq, q_buf, NTOK, QROW, 2048);
    gemm_nt<<<dim3((KV_LORA + D_ROPE) / 64, NTOK / 64), blk, 0, stream>>>(x, wkv_a, kv_raw, NTOK, KV_LORA + D_ROPE, 2048);
    kv_fix<<<dim3(NTOK), blk, 0, stream>>>(kv_raw, knw, fcos, fsin, kvn, kpe);
    gemm_nt<<<dim3(KVBROW / 64, NTOK / 64), blk, 0, stream>>>(kvn, wkv_b, kvb, NTOK, KVBROW, KV_LORA);
    attn_kernel<<<dim3(SEQ / 64, NH, NB), blk, 0, stream>>>(q_buf, kvb, kpe, att, scale);
    gemm_nt<<<dim3(2048 / 64, NTOK / 64), blk, 0, stream>>>(att, wo, out, NTOK, 2048, 2048);
}

// Round 3
// 1881.046 us; speedup vs baseline: 1.7581x; 1.7581x over previous
//
#include <hip/hip_runtime.h>
#include <math.h>

#define NH      16
#define D_NOPE  128
#define D_ROPE  64
#define D_QK    192
#define D_V     128
#define KV_LORA 512
#define NB      2
#define SEQ     2048
#define NTOK    (NB*SEQ)          // 4096
#define QROW    (NH*D_QK)         // 3072
#define KVBROW  (NH*(D_NOPE+D_V)) // 4096
#define EPSF    1e-6f

typedef unsigned short u16;
typedef float  floatx4 __attribute__((ext_vector_type(4)));
typedef __bf16 bf16x8  __attribute__((ext_vector_type(8)));
typedef u16    u16x4   __attribute__((ext_vector_type(4)));
typedef u16    u16x8   __attribute__((ext_vector_type(8)));

__device__ __forceinline__ u16 f2bf(float f) {
    unsigned u = __builtin_bit_cast(unsigned, f);
    return (u16)((u + 0x7fffu + ((u >> 16) & 1u)) >> 16);
}

__device__ __forceinline__ void async_copy16(const void* g, void* l) {
    __builtin_amdgcn_global_load_lds(
        (const __attribute__((address_space(1))) unsigned int*)g,
        (__attribute__((address_space(3))) unsigned int*)l,
        16, 0, 0);
}

// ---------------------------------------------------------------------------
// fp32 -> bf16 cast, 4 elems/thread.
// ---------------------------------------------------------------------------
__global__ __launch_bounds__(256) void cast_bf16(const float* __restrict__ in,
                                                 u16* __restrict__ out) {
    const int i = (blockIdx.x * 256 + threadIdx.x) * 4;
    const float4 v = *(const float4*)&in[i];
    u16x4 o; o[0] = f2bf(v.x); o[1] = f2bf(v.y); o[2] = f2bf(v.z); o[3] = f2bf(v.w);
    *(u16x4*)&out[i] = o;
}

// ---------------------------------------------------------------------------
// bf16 NT MFMA GEMM (m97 recipe): C[M,N] fp32 = A[M,K]bf16 @ B[N,K]bf16^T.
// Block 256 = 4 waves; tile 128x128; wave quadrant 64x64 (4x4 of 16x16x32).
// M,N mult of 128; K mult of 32.
// ---------------------------------------------------------------------------
__global__ __launch_bounds__(256) void gemm_nt_mfma(const u16* __restrict__ A,
                                                    const u16* __restrict__ B,
                                                    float* __restrict__ C,
                                                    int M, int N, int K) {
    __shared__ u16 As[128 * 32];   // row-major [128][32], 64 B/row — NO padding
    __shared__ u16 Bs[128 * 32];   // (global_load_lds layout constraint)
    const int tid  = threadIdx.x;
    const int wave = tid >> 6, lane = tid & 63;
    const int m0 = blockIdx.y * 128, n0 = blockIdx.x * 128;
    const int wm = (wave & 1) * 64, wn = (wave >> 1) * 64;

    // staging: per wave, 2 calls of 16 rows each for A and B
    const int srow = wave * 32 + (lane >> 2);   // 16 rows per call
    const int kch  = (lane & 3) * 8;            // 8 bf16 = 16 B chunk
    const u16* gA0 = A + (size_t)(m0 + srow) * K + kch;
    const u16* gA1 = gA0 + (size_t)16 * K;
    const u16* gB0 = B + (size_t)(n0 + srow) * K + kch;
    const u16* gB1 = gB0 + (size_t)16 * K;
    u16* lA0 = &As[(wave * 32) * 32];
    u16* lA1 = &As[(wave * 32 + 16) * 32];
    u16* lB0 = &Bs[(wave * 32) * 32];
    u16* lB1 = &Bs[(wave * 32 + 16) * 32];

    floatx4 acc[4][4];
#pragma unroll
    for (int i = 0; i < 4; ++i)
#pragma unroll
        for (int j = 0; j < 4; ++j) acc[i][j] = 0.f;

    const int lrow = lane & 15;
    const int lkh  = (lane >> 4) * 8;

    for (int k0 = 0; k0 < K; k0 += 32) {
        __syncthreads();
        async_copy16(gA0 + k0, lA0);
        async_copy16(gA1 + k0, lA1);
        async_copy16(gB0 + k0, lB0);
        async_copy16(gB1 + k0, lB1);
        __syncthreads();
        bf16x8 a[4], b[4];
#pragma unroll
        for (int mi = 0; mi < 4; ++mi)
            a[mi] = *(const bf16x8*)&As[(wm + mi * 16 + lrow) * 32 + lkh];
#pragma unroll
        for (int ni = 0; ni < 4; ++ni)
            b[ni] = *(const bf16x8*)&Bs[(wn + ni * 16 + lrow) * 32 + lkh];
#pragma unroll
        for (int mi = 0; mi < 4; ++mi)
#pragma unroll
            for (int ni = 0; ni < 4; ++ni)
                acc[mi][ni] = __builtin_amdgcn_mfma_f32_16x16x32_bf16(
                    a[mi], b[ni], acc[mi][ni], 0, 0, 0);
    }

    // C/D layout: col = lane&15, row = (lane>>4)*4 + reg
    const int crow = (lane >> 4) * 4, ccol = lane & 15;
#pragma unroll
    for (int mi = 0; mi < 4; ++mi)
#pragma unroll
        for (int ni = 0; ni < 4; ++ni) {
            float* cp = C + (size_t)(m0 + wm + mi * 16 + crow) * N + (n0 + wn + ni * 16 + ccol);
#pragma unroll
            for (int r = 0; r < 4; ++r) cp[(size_t)r * N] = acc[mi][ni][r];
        }
}

// ---------------------------------------------------------------------------
// fp32 tiled NT GEMM (kept for the N=576 wkv_a projection).
// ---------------------------------------------------------------------------
__global__ __launch_bounds__(256) void gemm_nt(const float* __restrict__ A,
                                               const float* __restrict__ B,
                                               float* __restrict__ C,
                                               int M, int N, int K) {
    __shared__ float As[16][64];
    __shared__ float Bs[16][64];
    const int tid = threadIdx.x;
    const int tx = tid & 15, ty = tid >> 4;
    const int m0 = blockIdx.y * 64, n0 = blockIdx.x * 64;
    const int lr = tid >> 2;
    const int lc = (tid & 3) * 4;
    float acc[4][4] = {};
    for (int k0 = 0; k0 < K; k0 += 16) {
        const float4 av = *(const float4*)&A[(size_t)(m0 + lr) * K + k0 + lc];
        const float4 bv = *(const float4*)&B[(size_t)(n0 + lr) * K + k0 + lc];
        __syncthreads();
        As[lc+0][lr] = av.x; As[lc+1][lr] = av.y; As[lc+2][lr] = av.z; As[lc+3][lr] = av.w;
        Bs[lc+0][lr] = bv.x; Bs[lc+1][lr] = bv.y; Bs[lc+2][lr] = bv.z; Bs[lc+3][lr] = bv.w;
        __syncthreads();
#pragma unroll
        for (int k = 0; k < 16; ++k) {
            const float4 a = *(const float4*)&As[k][ty * 4];
            const float4 b = *(const float4*)&Bs[k][tx * 4];
            acc[0][0] += a.x*b.x; acc[0][1] += a.x*b.y; acc[0][2] += a.x*b.z; acc[0][3] += a.x*b.w;
            acc[1][0] += a.y*b.x; acc[1][1] += a.y*b.y; acc[1][2] += a.y*b.z; acc[1][3] += a.y*b.w;
            acc[2][0] += a.z*b.x; acc[2][1] += a.z*b.y; acc[2][2] += a.z*b.z; acc[2][3] += a.z*b.w;
            acc[3][0] += a.w*b.x; acc[3][1] += a.w*b.y; acc[3][2] += a.w*b.z; acc[3][3] += a.w*b.w;
        }
    }
#pragma unroll
    for (int i = 0; i < 4; ++i) {
        float4 o = make_float4(acc[i][0], acc[i][1], acc[i][2], acc[i][3]);
        *(float4*)&C[(size_t)(m0 + ty * 4 + i) * N + n0 + tx * 4] = o;
    }
}

// NOTE: the reference computes q_pe = rotary(q_pe) but then uses the ORIGINAL
// (unrotated) q in the score einsum — the rotated q_pe is dead code there.
// So q gets NO RoPE; only k_pe is rotated.

// ---------------------------------------------------------------------------
// Per-token: rmsnorm(kv_c)*w -> kvn_bf (bf16); rotary(k_pe) -> kpe fp32.
// ---------------------------------------------------------------------------
__global__ __launch_bounds__(256) void kv_fix(const float* __restrict__ kv_raw,
                                              const float* __restrict__ w,
                                              const float* __restrict__ fcos,
                                              const float* __restrict__ fsin,
                                              u16* __restrict__ kvn_bf,
                                              float* __restrict__ kpe) {
    const int row = blockIdx.x;
    const int tid = threadIdx.x;
    const float* src = kv_raw + (size_t)row * (KV_LORA + D_ROPE);
    const float v0 = src[tid];
    const float v1 = src[256 + tid];
    float ss = v0 * v0 + v1 * v1;
#pragma unroll
    for (int off = 32; off > 0; off >>= 1) ss += __shfl_down(ss, off, 64);
    __shared__ float red[4];
    if ((tid & 63) == 0) red[tid >> 6] = ss;
    __syncthreads();
    const float tot = red[0] + red[1] + red[2] + red[3];
    const float inv = rsqrtf(tot * (1.0f / KV_LORA) + EPSF);
    kvn_bf[(size_t)row * KV_LORA + tid]       = f2bf(v0 * inv * w[tid]);
    kvn_bf[(size_t)row * KV_LORA + 256 + tid] = f2bf(v1 * inv * w[256 + tid]);
    if (tid < 32) {
        const int s = row & (SEQ - 1);
        const float c  = fcos[s * 32 + tid];
        const float sn = fsin[s * 32 + tid];
        const float xr = src[KV_LORA + 2 * tid];
        const float xi = src[KV_LORA + 2 * tid + 1];
        kpe[(size_t)row * D_ROPE + 2 * tid]     = xr * c - xi * sn;
        kpe[(size_t)row * D_ROPE + 2 * tid + 1] = xr * sn + xi * c;
    }
}

// ---------------------------------------------------------------------------
// Causal flash attention, fp32 (unchanged this round except bf16 att output).
// ---------------------------------------------------------------------------
__global__ __launch_bounds__(256) void attn_kernel(const float* __restrict__ qbuf,
                                                   const float* __restrict__ kvb,
                                                   const float* __restrict__ kpe,
                                                   u16* __restrict__ att,
                                                   float scale) {
    __shared__ float smem[12544];
    const int qt = blockIdx.x, h = blockIdx.y, b = blockIdx.z;
    const int tid = threadIdx.x;
    const int tx = tid & 15, ty = tid >> 4;
    const int row0 = b * SEQ + qt * 64;

    float oacc[4][8];
#pragma unroll
    for (int i = 0; i < 4; ++i)
#pragma unroll
        for (int j = 0; j < 8; ++j) oacc[i][j] = 0.f;
    float mrow[4], lrow[4];
#pragma unroll
    for (int i = 0; i < 4; ++i) { mrow[i] = -1e30f; lrow[i] = 0.f; }

    for (int tt = 0; tt <= qt; ++tt) {
        const int t0 = tt * 64;
        float sacc[4][4] = {};
        for (int dc = 0; dc < 3; ++dc) {
            __syncthreads();
            const int dl = (tid & 15) * 4;
#pragma unroll
            for (int mi = 0; mi < 4; ++mi) {
                const int m = (tid >> 4) + 16 * mi;
                const float4 qv = *(const float4*)&qbuf[(size_t)(row0 + m) * QROW + h * D_QK + dc * 64 + dl];
                smem[(dl+0)*68 + m] = qv.x; smem[(dl+1)*68 + m] = qv.y;
                smem[(dl+2)*68 + m] = qv.z; smem[(dl+3)*68 + m] = qv.w;
                const float4 kv = (dc < 2)
                    ? *(const float4*)&kvb[(size_t)(b * SEQ + t0 + m) * KVBROW + h * 256 + dc * 64 + dl]
                    : *(const float4*)&kpe[(size_t)(b * SEQ + t0 + m) * D_ROPE + dl];
                smem[4352 + (dl+0)*68 + m] = kv.x; smem[4352 + (dl+1)*68 + m] = kv.y;
                smem[4352 + (dl+2)*68 + m] = kv.z; smem[4352 + (dl+3)*68 + m] = kv.w;
            }
            __syncthreads();
#pragma unroll 8
            for (int k = 0; k < 64; ++k) {
                const float4 a = *(const float4*)&smem[k * 68 + ty * 4];
                const float4 bb = *(const float4*)&smem[4352 + k * 68 + tx * 4];
                sacc[0][0] += a.x*bb.x; sacc[0][1] += a.x*bb.y; sacc[0][2] += a.x*bb.z; sacc[0][3] += a.x*bb.w;
                sacc[1][0] += a.y*bb.x; sacc[1][1] += a.y*bb.y; sacc[1][2] += a.y*bb.z; sacc[1][3] += a.y*bb.w;
                sacc[2][0] += a.z*bb.x; sacc[2][1] += a.z*bb.y; sacc[2][2] += a.z*bb.z; sacc[2][3] += a.z*bb.w;
                sacc[3][0] += a.w*bb.x; sacc[3][1] += a.w*bb.y; sacc[3][2] += a.w*bb.z; sacc[3][3] += a.w*bb.w;
            }
        }
        float p[4][4];
#pragma unroll
        for (int i = 0; i < 4; ++i) {
            const int srow = qt * 64 + ty * 4 + i;
            float sv[4];
#pragma unroll
            for (int j = 0; j < 4; ++j) {
                const int tcol = t0 + tx * 4 + j;
                sv[j] = (tcol <= srow) ? sacc[i][j] * scale : -1e30f;
            }
            float rmax = fmaxf(fmaxf(sv[0], sv[1]), fmaxf(sv[2], sv[3]));
            rmax = fmaxf(rmax, __shfl_xor(rmax, 1));
            rmax = fmaxf(rmax, __shfl_xor(rmax, 2));
            rmax = fmaxf(rmax, __shfl_xor(rmax, 4));
            rmax = fmaxf(rmax, __shfl_xor(rmax, 8));
            const float mnew = fmaxf(mrow[i], rmax);
            const float alpha = __expf(mrow[i] - mnew);
            mrow[i] = mnew;
            float rsum = 0.f;
#pragma unroll
            for (int j = 0; j < 4; ++j) { p[i][j] = __expf(sv[j] - mnew); rsum += p[i][j]; }
            rsum += __shfl_xor(rsum, 1);
            rsum += __shfl_xor(rsum, 2);
            rsum += __shfl_xor(rsum, 4);
            rsum += __shfl_xor(rsum, 8);
            lrow[i] = lrow[i] * alpha + rsum;
#pragma unroll
            for (int j = 0; j < 8; ++j) oacc[i][j] *= alpha;
        }
        __syncthreads();
#pragma unroll
        for (int j = 0; j < 4; ++j) {
            float4 pc = make_float4(p[0][j], p[1][j], p[2][j], p[3][j]);
            *(float4*)&smem[(tx * 4 + j) * 68 + ty * 4] = pc;
        }
        {
            const int dv = (tid & 31) * 4;
            const int tb = tid >> 5;
#pragma unroll
            for (int vi = 0; vi < 8; ++vi) {
                const int tp = tb + 8 * vi;
                const float4 vv = *(const float4*)&kvb[(size_t)(b * SEQ + t0 + tp) * KVBROW + h * 256 + D_NOPE + dv];
                *(float4*)&smem[4352 + tp * 128 + dv] = vv;
            }
        }
        __syncthreads();
#pragma unroll 8
        for (int k = 0; k < 64; ++k) {
            const float4 pv = *(const float4*)&smem[k * 68 + ty * 4];
            const float4 v0 = *(const float4*)&smem[4352 + k * 128 + tx * 8];
            const float4 v1 = *(const float4*)&smem[4352 + k * 128 + tx * 8 + 4];
            oacc[0][0] += pv.x*v0.x; oacc[0][1] += pv.x*v0.y; oacc[0][2] += pv.x*v0.z; oacc[0][3] += pv.x*v0.w;
            oacc[0][4] += pv.x*v1.x; oacc[0][5] += pv.x*v1.y; oacc[0][6] += pv.x*v1.z; oacc[0][7] += pv.x*v1.w;
            oacc[1][0] += pv.y*v0.x; oacc[1][1] += pv.y*v0.y; oacc[1][2] += pv.y*v0.z; oacc[1][3] += pv.y*v0.w;
            oacc[1][4] += pv.y*v1.x; oacc[1][5] += pv.y*v1.y; oacc[1][6] += pv.y*v1.z; oacc[1][7] += pv.y*v1.w;
            oacc[2][0] += pv.z*v0.x; oacc[2][1] += pv.z*v0.y; oacc[2][2] += pv.z*v0.z; oacc[2][3] += pv.z*v0.w;
            oacc[2][4] += pv.z*v1.x; oacc[2][5] += pv.z*v1.y; oacc[2][6] += pv.z*v1.z; oacc[2][7] += pv.z*v1.w;
            oacc[3][0] += pv.w*v0.x; oacc[3][1] += pv.w*v0.y; oacc[3][2] += pv.w*v0.z; oacc[3][3] += pv.w*v0.w;
            oacc[3][4] += pv.w*v1.x; oacc[3][5] += pv.w*v1.y; oacc[3][6] += pv.w*v1.z; oacc[3][7] += pv.w*v1.w;
        }
    }
#pragma unroll
    for (int i = 0; i < 4; ++i) {
        const float inv = 1.0f / lrow[i];
        u16x8 o;
#pragma unroll
        for (int j = 0; j < 8; ++j) o[j] = f2bf(oacc[i][j] * inv);
        *(u16x8*)&att[(size_t)(row0 + ty * 4 + i) * (NH * D_V) + h * D_V + tx * 8] = o;
    }
}

// ---------------------------------------------------------------------------
extern "C" void kernel_launch(void* const* d_in, const int* in_sizes, int n_in,
                              void* d_out, int out_size, void* d_ws, size_t ws_size,
                              hipStream_t stream) {
    const float* x     = (const float*)d_in[0];
    const float* wq    = (const float*)d_in[1];
    const float* wkv_a = (const float*)d_in[2];
    const float* knw   = (const float*)d_in[3];
    const float* wkv_b = (const float*)d_in[4];
    const float* wo    = (const float*)d_in[5];
    const float* fcos  = (const float*)d_in[6];
    const float* fsin  = (const float*)d_in[7];
    float* out = (float*)d_out;

    // Workspace layout with lifetime aliasing (total 168.8 MB):
    char* w = (char*)d_ws;
    float* q_buf   = (float*)w;  w += (size_t)NTOK * QROW * 4;      // 50.3 MB [G1 -> attn]
    float* kvb     = (float*)w;  w += (size_t)NTOK * KVBROW * 4;    // 67.1 MB [G3 -> attn]
    float* kpe     = (float*)w;  w += (size_t)NTOK * D_ROPE * 4;    //  1.0 MB
    u16*   x_bf    = (u16*)w;                                       // 16.8 MB [cast -> G1]
    float* kv_raw  = (float*)w;  w += (size_t)NTOK * 2048 * 2;      //   alias: [G2 -> kv_fix]
    u16*   wq_bf   = (u16*)w;                                       // 12.6 MB [cast -> G1]
    u16*   att_bf  = (u16*)w;    w += (size_t)NTOK * 2048 * 2;      //   alias: [attn -> G4]
    u16*   wkvb_bf = (u16*)w;    w += (size_t)KVBROW * KV_LORA * 2; //  4.2 MB
    u16*   wo_bf   = (u16*)w;    w += (size_t)2048 * 2048 * 2;      //  8.4 MB
    u16*   kvn_bf  = (u16*)w;    w += (size_t)NTOK * KV_LORA * 2;   //  4.2 MB

    const double mm = 0.1 * 1.0 * log(40.0) + 1.0;
    const float scale = (float)((1.0 / sqrt((double)D_QK)) * mm * mm);

    dim3 blk(256);
    // casts
    cast_bf16<<<dim3(NTOK * 2048 / 1024), blk, 0, stream>>>(x, x_bf);
    cast_bf16<<<dim3(QROW * 2048 / 1024), blk, 0, stream>>>(wq, wq_bf);
    cast_bf16<<<dim3(KVBROW * KV_LORA / 1024), blk, 0, stream>>>(wkv_b, wkvb_bf);
    cast_bf16<<<dim3(2048 * 2048 / 1024), blk, 0, stream>>>(wo, wo_bf);
    // G1: q = x @ wq^T  (MFMA)
    gemm_nt_mfma<<<dim3(QROW / 128, NTOK / 128), blk, 0, stream>>>(x_bf, wq_bf, q_buf, NTOK, QROW, 2048);
    // G2: kv_raw = x @ wkv_a^T  (fp32; N=576 not 128-divisible; overwrites dead x_bf)
    gemm_nt<<<dim3((KV_LORA + D_ROPE) / 64, NTOK / 64), blk, 0, stream>>>(x, wkv_a, kv_raw, NTOK, KV_LORA + D_ROPE, 2048);
    kv_fix<<<dim3(NTOK), blk, 0, stream>>>(kv_raw, knw, fcos, fsin, kvn_bf, kpe);
    // G3: kvb = kvn @ wkv_b^T  (MFMA)
    gemm_nt_mfma<<<dim3(KVBROW / 128, NTOK / 128), blk, 0, stream>>>(kvn_bf, wkvb_bf, kvb, NTOK, KVBROW, KV_LORA);
    attn_kernel<<<dim3(SEQ / 64, NH, NB), blk, 0, stream>>>(q_buf, kvb, kpe, att_bf, scale);
    // G4: out = att @ wo^T  (MFMA)
    gemm_nt_mfma<<<dim3(2048 / 128, NTOK / 128), blk, 0, stream>>>(att_bf, wo_bf, out, NTOK, 2048, 2048);
}

// Round 4
// 511.209 us; speedup vs baseline: 6.4692x; 3.6796x over previous
//
#include <hip/hip_runtime.h>
#include <math.h>

#define NH      16
#define D_NOPE  128
#define D_ROPE  64
#define D_QK    192
#define D_V     128
#define KV_LORA 512
#define NB      2
#define SEQ     2048
#define NTOK    (NB*SEQ)          // 4096
#define QROW    (NH*D_QK)         // 3072
#define KVBROW  (NH*(D_NOPE+D_V)) // 4096
#define EPSF    1e-6f

typedef unsigned short u16;
typedef float  floatx4 __attribute__((ext_vector_type(4)));
typedef __bf16 bf16x8  __attribute__((ext_vector_type(8)));
typedef u16    u16x4   __attribute__((ext_vector_type(4)));
typedef u16    u16x8   __attribute__((ext_vector_type(8)));

__device__ __forceinline__ u16 f2bf(float f) {
    unsigned u = __builtin_bit_cast(unsigned, f);
    return (u16)((u + 0x7fffu + ((u >> 16) & 1u)) >> 16);
}

__device__ __forceinline__ void async_copy16(const void* g, void* l) {
    __builtin_amdgcn_global_load_lds(
        (const __attribute__((address_space(1))) unsigned int*)g,
        (__attribute__((address_space(3))) unsigned int*)l,
        16, 0, 0);
}

// ---------------------------------------------------------------------------
// fp32 -> bf16 cast, 4 elems/thread.
// ---------------------------------------------------------------------------
__global__ __launch_bounds__(256) void cast_bf16(const float* __restrict__ in,
                                                 u16* __restrict__ out) {
    const int i = (blockIdx.x * 256 + threadIdx.x) * 4;
    const float4 v = *(const float4*)&in[i];
    u16x4 o; o[0] = f2bf(v.x); o[1] = f2bf(v.y); o[2] = f2bf(v.z); o[3] = f2bf(v.w);
    *(u16x4*)&out[i] = o;
}

// wkv_a (576x2048 fp32) -> padded 640x2048 bf16 (rows 576..639 zero).
__global__ __launch_bounds__(256) void cast_pad_wkva(const float* __restrict__ in,
                                                     u16* __restrict__ out) {
    const int i = (blockIdx.x * 256 + threadIdx.x) * 4;   // over 640*2048
    const int r = i >> 11;
    u16x4 o;
    if (r < 576) {
        const float4 v = *(const float4*)&in[i];
        o[0] = f2bf(v.x); o[1] = f2bf(v.y); o[2] = f2bf(v.z); o[3] = f2bf(v.w);
    } else {
        o[0] = 0; o[1] = 0; o[2] = 0; o[3] = 0;
    }
    *(u16x4*)&out[i] = o;
}

// ---------------------------------------------------------------------------
// bf16 NT MFMA GEMM (m97 recipe), templated epilogue:
//   MODE 0: fp32 C[M,N]
//   MODE 1: bf16 C[M,N]
//   MODE 2: kv-split: cols j<128 of each head's 256 -> kbuf[h][b][t][192] (k_nope),
//           cols j>=128 -> vT[h][b][j-128][2048] (transposed V), both bf16.
// Block 256 = 4 waves; tile 128x128; M,N mult of 128; K mult of 32.
// ---------------------------------------------------------------------------
template<int MODE>
__global__ __launch_bounds__(256) void gemm_mfma(const u16* __restrict__ A,
                                                 const u16* __restrict__ B,
                                                 void* __restrict__ Cout,
                                                 u16* __restrict__ kbuf,
                                                 u16* __restrict__ vT,
                                                 int M, int N, int K) {
    __shared__ u16 As[128 * 32];
    __shared__ u16 Bs[128 * 32];
    const int tid  = threadIdx.x;
    const int wave = tid >> 6, lane = tid & 63;
    const int m0 = blockIdx.y * 128, n0 = blockIdx.x * 128;
    const int wm = (wave & 1) * 64, wn = (wave >> 1) * 64;

    const int srow = wave * 32 + (lane >> 2);
    const int kch  = (lane & 3) * 8;
    const u16* gA0 = A + (size_t)(m0 + srow) * K + kch;
    const u16* gA1 = gA0 + (size_t)16 * K;
    const u16* gB0 = B + (size_t)(n0 + srow) * K + kch;
    const u16* gB1 = gB0 + (size_t)16 * K;
    u16* lA0 = &As[(wave * 32) * 32];
    u16* lA1 = &As[(wave * 32 + 16) * 32];
    u16* lB0 = &Bs[(wave * 32) * 32];
    u16* lB1 = &Bs[(wave * 32 + 16) * 32];

    floatx4 acc[4][4];
#pragma unroll
    for (int i = 0; i < 4; ++i)
#pragma unroll
        for (int j = 0; j < 4; ++j) acc[i][j] = 0.f;

    const int lrow = lane & 15;
    const int lkh  = (lane >> 4) * 8;

    for (int k0 = 0; k0 < K; k0 += 32) {
        __syncthreads();
        async_copy16(gA0 + k0, lA0);
        async_copy16(gA1 + k0, lA1);
        async_copy16(gB0 + k0, lB0);
        async_copy16(gB1 + k0, lB1);
        __syncthreads();
        bf16x8 a[4], b[4];
#pragma unroll
        for (int mi = 0; mi < 4; ++mi)
            a[mi] = *(const bf16x8*)&As[(wm + mi * 16 + lrow) * 32 + lkh];
#pragma unroll
        for (int ni = 0; ni < 4; ++ni)
            b[ni] = *(const bf16x8*)&Bs[(wn + ni * 16 + lrow) * 32 + lkh];
#pragma unroll
        for (int mi = 0; mi < 4; ++mi)
#pragma unroll
            for (int ni = 0; ni < 4; ++ni)
                acc[mi][ni] = __builtin_amdgcn_mfma_f32_16x16x32_bf16(
                    a[mi], b[ni], acc[mi][ni], 0, 0, 0);
    }

    const int crow = (lane >> 4) * 4, ccol = lane & 15;
#pragma unroll
    for (int mi = 0; mi < 4; ++mi)
#pragma unroll
        for (int ni = 0; ni < 4; ++ni) {
            const int m = m0 + wm + mi * 16 + crow;
            const int c = n0 + wn + ni * 16 + ccol;
            if (MODE == 0) {
                float* cp = (float*)Cout + (size_t)m * N + c;
#pragma unroll
                for (int r = 0; r < 4; ++r) cp[(size_t)r * N] = acc[mi][ni][r];
            } else if (MODE == 1) {
                u16* cp = (u16*)Cout + (size_t)m * N + c;
#pragma unroll
                for (int r = 0; r < 4; ++r) cp[(size_t)r * N] = f2bf(acc[mi][ni][r]);
            } else {
                const int hh = c >> 8, j = c & 255;
                const int bb = m >> 11, t = m & 2047;
                if (j < 128) {
#pragma unroll
                    for (int r = 0; r < 4; ++r)
                        kbuf[(((size_t)hh * 2 + bb) * 2048 + t + r) * 192 + j] =
                            f2bf(acc[mi][ni][r]);
                } else {
                    u16x4 pk;
#pragma unroll
                    for (int r = 0; r < 4; ++r) pk[r] = f2bf(acc[mi][ni][r]);
                    *(u16x4*)&vT[(((size_t)hh * 2 + bb) * 128 + (j - 128)) * 2048 + t] = pk;
                }
            }
        }
}

// NOTE: the reference computes q_pe = rotary(q_pe) but then uses the ORIGINAL
// (unrotated) q in the score einsum — the rotated q_pe is dead code there.
// So q gets NO RoPE; only k_pe is rotated.

// ---------------------------------------------------------------------------
// Per-token: rmsnorm(kv_c)*w -> kvn_bf; rotary(k_pe) -> kbuf[h][b][t][128..191]
// for all heads. kv_raw row stride 640 (padded G2 output).
// ---------------------------------------------------------------------------
__global__ __launch_bounds__(256) void kv_fix(const float* __restrict__ kv_raw,
                                              const float* __restrict__ w,
                                              const float* __restrict__ fcos,
                                              const float* __restrict__ fsin,
                                              u16* __restrict__ kvn_bf,
                                              u16* __restrict__ kbuf) {
    const int row = blockIdx.x;
    const int tid = threadIdx.x;
    const float* src = kv_raw + (size_t)row * 640;
    const float v0 = src[tid];
    const float v1 = src[256 + tid];
    float ss = v0 * v0 + v1 * v1;
#pragma unroll
    for (int off = 32; off > 0; off >>= 1) ss += __shfl_down(ss, off, 64);
    __shared__ float red[4];
    __shared__ float kpe_s[64];
    if ((tid & 63) == 0) red[tid >> 6] = ss;
    if (tid < 32) {
        const int s = row & (SEQ - 1);
        const float c  = fcos[s * 32 + tid];
        const float sn = fsin[s * 32 + tid];
        const float xr = src[KV_LORA + 2 * tid];
        const float xi = src[KV_LORA + 2 * tid + 1];
        kpe_s[2 * tid]     = xr * c - xi * sn;
        kpe_s[2 * tid + 1] = xr * sn + xi * c;
    }
    __syncthreads();
    const float tot = red[0] + red[1] + red[2] + red[3];
    const float inv = rsqrtf(tot * (1.0f / KV_LORA) + EPSF);
    kvn_bf[(size_t)row * KV_LORA + tid]       = f2bf(v0 * inv * w[tid]);
    kvn_bf[(size_t)row * KV_LORA + 256 + tid] = f2bf(v1 * inv * w[256 + tid]);
    // broadcast rotated k_pe to all 16 heads in kbuf
    const int bb = row >> 11, t = row & 2047;
    const int hh = tid >> 4, dg = (tid & 15) * 4;
    u16x4 pk;
#pragma unroll
    for (int j = 0; j < 4; ++j) pk[j] = f2bf(kpe_s[dg + j]);
    *(u16x4*)&kbuf[(((size_t)hh * 2 + bb) * 2048 + t) * 192 + 128 + dg] = pk;
}

// ---------------------------------------------------------------------------
// MFMA flash attention. Block 256 = 4 waves; one (b,h,64-row q-tile) per block.
// Wave w owns q rows qt*64 + w*16 .. +15.
// S^T = K @ Q^T (A=K, B=Q, C[t][q]); softmax per q-col (lane&15);
// P -> Ps[q][t] via ds_write_b64; O[q][v] = P @ (V^T)^T (A=P, B=V^T).
// LDS: Ks[6][64][32] 24KB + Vs[2][128][32] 16KB + Ps[4][16][72] 9KB = 49KB.
// ---------------------------------------------------------------------------
__global__ __launch_bounds__(256) void attn_mfma(const u16* __restrict__ qbf,
                                                 const u16* __restrict__ kbuf,
                                                 const u16* __restrict__ vT,
                                                 u16* __restrict__ att,
                                                 float scale) {
    __shared__ __attribute__((aligned(16))) u16 Ks[6 * 64 * 32];
    __shared__ __attribute__((aligned(16))) u16 Vs[2 * 128 * 32];
    __shared__ __attribute__((aligned(16))) u16 Ps[4][16 * 72];
    const int qt = blockIdx.x, h = blockIdx.y, b = blockIdx.z;
    const int tid = threadIdx.x, wave = tid >> 6, lane = tid & 63;
    const int l15 = lane & 15, lg = lane >> 4;

    // Q B-frags for this wave's 16 q-rows, hoisted over the whole tt loop
    const int qrow = qt * 64 + wave * 16 + l15;            // seq-local q position
    const size_t qoff = ((size_t)(b * SEQ + qrow)) * QROW + h * 192 + lg * 8;
    bf16x8 qf[6];
#pragma unroll
    for (int s = 0; s < 6; ++s) qf[s] = *(const bf16x8*)&qbf[qoff + s * 32];

    const u16* kb_base = kbuf + ((size_t)(h * 2 + b)) * 2048 * 192;
    const u16* vt_base = vT   + ((size_t)(h * 2 + b)) * 128 * 2048;

    floatx4 oacc[8];
#pragma unroll
    for (int v = 0; v < 8; ++v) oacc[v] = 0.f;
    float m_run = -1e30f, l_run = 0.f;

    for (int tt = 0; tt <= qt; ++tt) {
        const int t0 = tt * 64;
        __syncthreads();
        // stage K tile [64][192] -> Ks[s][t][32]; 24 calls, 6 per wave
#pragma unroll
        for (int i = 0; i < 6; ++i) {
            const int base = (wave * 6 + i) * 64;
            const int slot = base + lane;
            const int s = slot >> 8, r = slot & 255, tk = r >> 2, ch = r & 3;
            async_copy16(kb_base + ((size_t)(t0 + tk)) * 192 + s * 32 + ch * 8,
                         &Ks[base * 8]);
        }
        // stage V^T tile [128][64] -> Vs[s][v][32]; 16 calls, 4 per wave
#pragma unroll
        for (int i = 0; i < 4; ++i) {
            const int base = (wave * 4 + i) * 64;
            const int slot = base + lane;
            const int s = slot >> 9, r = slot & 511, v = r >> 2, ch = r & 3;
            async_copy16(vt_base + ((size_t)v) * 2048 + t0 + s * 32 + ch * 8,
                         &Vs[base * 8]);
        }
        __syncthreads();
        // S^T[64t][16q]: 4 token-tiles x 6 ksteps
        floatx4 sacc[4];
#pragma unroll
        for (int mt = 0; mt < 4; ++mt) sacc[mt] = 0.f;
#pragma unroll
        for (int s = 0; s < 6; ++s) {
#pragma unroll
            for (int mt = 0; mt < 4; ++mt) {
                const bf16x8 kf = *(const bf16x8*)&Ks[(s * 64 + mt * 16 + l15) * 32 + lg * 8];
                sacc[mt] = __builtin_amdgcn_mfma_f32_16x16x32_bf16(kf, qf[s], sacc[mt], 0, 0, 0);
            }
        }
        // online softmax per q-col (this lane's q = qrow)
        float p[16];
        float tmax = -1e30f;
#pragma unroll
        for (int mt = 0; mt < 4; ++mt)
#pragma unroll
            for (int r = 0; r < 4; ++r) {
                const int tglob = t0 + mt * 16 + lg * 4 + r;
                float v = sacc[mt][r] * scale;
                v = (tglob <= qrow) ? v : -1e30f;
                p[mt * 4 + r] = v;
                tmax = fmaxf(tmax, v);
            }
        tmax = fmaxf(tmax, __shfl_xor(tmax, 16));
        tmax = fmaxf(tmax, __shfl_xor(tmax, 32));
        const float mnew = fmaxf(m_run, tmax);
        const float alpha = __expf(m_run - mnew);
        m_run = mnew;
        float rsum = 0.f;
#pragma unroll
        for (int k = 0; k < 16; ++k) { p[k] = __expf(p[k] - mnew); rsum += p[k]; }
        rsum += __shfl_xor(rsum, 16);
        rsum += __shfl_xor(rsum, 32);
        l_run = l_run * alpha + rsum;
        // write P -> Ps[wave][q][t] (4 consecutive tokens per reg-group)
#pragma unroll
        for (int mt = 0; mt < 4; ++mt) {
            u16x4 pk;
#pragma unroll
            for (int r = 0; r < 4; ++r) pk[r] = f2bf(p[mt * 4 + r]);
            *(u16x4*)&Ps[wave][l15 * 72 + mt * 16 + lg * 4] = pk;
        }
        // rescale O by alpha per q-row (broadcast from lane owning that q)
        float af[4];
#pragma unroll
        for (int r = 0; r < 4; ++r) af[r] = __shfl(alpha, lg * 4 + r);
#pragma unroll
        for (int vt = 0; vt < 8; ++vt)
#pragma unroll
            for (int r = 0; r < 4; ++r) oacc[vt][r] *= af[r];
        // O[16q][128v] += P @ V : 8 v-tiles x 2 ksteps
#pragma unroll
        for (int s = 0; s < 2; ++s) {
            const bf16x8 pf = *(const bf16x8*)&Ps[wave][l15 * 72 + s * 32 + lg * 8];
#pragma unroll
            for (int vt = 0; vt < 8; ++vt) {
                const bf16x8 vf = *(const bf16x8*)&Vs[(s * 128 + vt * 16 + l15) * 32 + lg * 8];
                oacc[vt] = __builtin_amdgcn_mfma_f32_16x16x32_bf16(pf, vf, oacc[vt], 0, 0, 0);
            }
        }
    }
    // epilogue: divide by l, store bf16
    float lf[4];
#pragma unroll
    for (int r = 0; r < 4; ++r) lf[r] = 1.0f / __shfl(l_run, lg * 4 + r);
#pragma unroll
    for (int vt = 0; vt < 8; ++vt)
#pragma unroll
        for (int r = 0; r < 4; ++r) {
            const int orow = b * SEQ + qt * 64 + wave * 16 + lg * 4 + r;
            att[(size_t)orow * 2048 + h * 128 + vt * 16 + l15] = f2bf(oacc[vt][r] * lf[r]);
        }
}

// ---------------------------------------------------------------------------
extern "C" void kernel_launch(void* const* d_in, const int* in_sizes, int n_in,
                              void* d_out, int out_size, void* d_ws, size_t ws_size,
                              hipStream_t stream) {
    const float* x     = (const float*)d_in[0];
    const float* wq    = (const float*)d_in[1];
    const float* wkv_a = (const float*)d_in[2];
    const float* knw   = (const float*)d_in[3];
    const float* wkv_b = (const float*)d_in[4];
    const float* wo    = (const float*)d_in[5];
    const float* fcos  = (const float*)d_in[6];
    const float* fsin  = (const float*)d_in[7];
    float* out = (float*)d_out;

    // Workspace (~143 MB, no aliasing needed):
    char* w = (char*)d_ws;
    u16*   x_bf    = (u16*)w;  w += (size_t)NTOK * 2048 * 2;        // 16.8 MB
    u16*   wq_bf   = (u16*)w;  w += (size_t)QROW * 2048 * 2;        // 12.6 MB
    u16*   wkva_bf = (u16*)w;  w += (size_t)640 * 2048 * 2;         //  2.6 MB
    u16*   wkvb_bf = (u16*)w;  w += (size_t)KVBROW * KV_LORA * 2;   //  4.2 MB
    u16*   wo_bf   = (u16*)w;  w += (size_t)2048 * 2048 * 2;        //  8.4 MB
    u16*   q_bf    = (u16*)w;  w += (size_t)NTOK * QROW * 2;        // 25.2 MB
    float* kv_raw  = (float*)w; w += (size_t)NTOK * 640 * 4;        // 10.5 MB
    u16*   kvn_bf  = (u16*)w;  w += (size_t)NTOK * KV_LORA * 2;     //  4.2 MB
    u16*   kbuf    = (u16*)w;  w += (size_t)NH * NB * SEQ * 192 * 2;// 25.2 MB
    u16*   vT      = (u16*)w;  w += (size_t)NH * NB * 128 * SEQ * 2;// 16.8 MB
    u16*   att_bf  = (u16*)w;  w += (size_t)NTOK * 2048 * 2;        // 16.8 MB

    const double mm = 0.1 * 1.0 * log(40.0) + 1.0;
    const float scale = (float)((1.0 / sqrt((double)D_QK)) * mm * mm);

    dim3 blk(256);
    cast_bf16<<<dim3(NTOK * 2048 / 1024), blk, 0, stream>>>(x, x_bf);
    cast_bf16<<<dim3(QROW * 2048 / 1024), blk, 0, stream>>>(wq, wq_bf);
    cast_pad_wkva<<<dim3(640 * 2048 / 1024), blk, 0, stream>>>(wkv_a, wkva_bf);
    cast_bf16<<<dim3(KVBROW * KV_LORA / 1024), blk, 0, stream>>>(wkv_b, wkvb_bf);
    cast_bf16<<<dim3(2048 * 2048 / 1024), blk, 0, stream>>>(wo, wo_bf);
    // G1: q_bf = x @ wq^T  (bf16 out)
    gemm_mfma<1><<<dim3(QROW / 128, NTOK / 128), blk, 0, stream>>>(
        x_bf, wq_bf, q_bf, nullptr, nullptr, NTOK, QROW, 2048);
    // G2: kv_raw = x @ wkv_a^T (padded to 640 cols, fp32 out)
    gemm_mfma<0><<<dim3(640 / 128, NTOK / 128), blk, 0, stream>>>(
        x_bf, wkva_bf, kv_raw, nullptr, nullptr, NTOK, 640, 2048);
    kv_fix<<<dim3(NTOK), blk, 0, stream>>>(kv_raw, knw, fcos, fsin, kvn_bf, kbuf);
    // G3: kvb = kvn @ wkv_b^T, split-scattered into kbuf (k_nope) + vT (V^T)
    gemm_mfma<2><<<dim3(KVBROW / 128, NTOK / 128), blk, 0, stream>>>(
        kvn_bf, wkvb_bf, nullptr, kbuf, vT, NTOK, KVBROW, KV_LORA);
    attn_mfma<<<dim3(SEQ / 64, NH, NB), blk, 0, stream>>>(q_bf, kbuf, vT, att_bf, scale);
    // G4: out = att @ wo^T (fp32 out)
    gemm_mfma<0><<<dim3(2048 / 128, NTOK / 128), blk, 0, stream>>>(
        att_bf, wo_bf, out, nullptr, nullptr, NTOK, 2048, 2048);
}

// Round 5
// 476.043 us; speedup vs baseline: 6.9471x; 1.0739x over previous
//
#include <hip/hip_runtime.h>
#include <math.h>

#define NH      16
#define D_NOPE  128
#define D_ROPE  64
#define D_QK    192
#define D_V     128
#define KV_LORA 512
#define NB      2
#define SEQ     2048
#define NTOK    (NB*SEQ)          // 4096
#define QROW    (NH*D_QK)         // 3072
#define KVBROW  (NH*(D_NOPE+D_V)) // 4096
#define EPSF    1e-6f

typedef unsigned short u16;
typedef float  floatx4 __attribute__((ext_vector_type(4)));
typedef __bf16 bf16x8  __attribute__((ext_vector_type(8)));
typedef u16    u16x4   __attribute__((ext_vector_type(4)));
typedef u16    u16x8   __attribute__((ext_vector_type(8)));

__device__ __forceinline__ u16 f2bf(float f) {
    unsigned u = __builtin_bit_cast(unsigned, f);
    return (u16)((u + 0x7fffu + ((u >> 16) & 1u)) >> 16);
}

__device__ __forceinline__ void async_copy16(const void* g, void* l) {
    __builtin_amdgcn_global_load_lds(
        (const __attribute__((address_space(1))) unsigned int*)g,
        (__attribute__((address_space(3))) unsigned int*)l,
        16, 0, 0);
}

// ---------------------------------------------------------------------------
// fp32 -> bf16 cast, 4 elems/thread.
// ---------------------------------------------------------------------------
__global__ __launch_bounds__(256) void cast_bf16(const float* __restrict__ in,
                                                 u16* __restrict__ out) {
    const int i = (blockIdx.x * 256 + threadIdx.x) * 4;
    const float4 v = *(const float4*)&in[i];
    u16x4 o; o[0] = f2bf(v.x); o[1] = f2bf(v.y); o[2] = f2bf(v.z); o[3] = f2bf(v.w);
    *(u16x4*)&out[i] = o;
}

// wkv_a (576x2048 fp32) -> padded 640x2048 bf16 (rows 576..639 zero).
__global__ __launch_bounds__(256) void cast_pad_wkva(const float* __restrict__ in,
                                                     u16* __restrict__ out) {
    const int i = (blockIdx.x * 256 + threadIdx.x) * 4;   // over 640*2048
    const int r = i >> 11;
    u16x4 o;
    if (r < 576) {
        const float4 v = *(const float4*)&in[i];
        o[0] = f2bf(v.x); o[1] = f2bf(v.y); o[2] = f2bf(v.z); o[3] = f2bf(v.w);
    } else {
        o[0] = 0; o[1] = 0; o[2] = 0; o[3] = 0;
    }
    *(u16x4*)&out[i] = o;
}

// ---------------------------------------------------------------------------
// bf16 NT MFMA GEMM (m97 recipe), templated epilogue:
//   MODE 0: fp32 C[M,N]
//   MODE 1: bf16 C[M,N]
//   MODE 2: kv-split: cols j<128 of each head's 256 -> kbuf (k_nope),
//           cols j>=128 -> vT (transposed V), both bf16.
// ---------------------------------------------------------------------------
template<int MODE>
__global__ __launch_bounds__(256) void gemm_mfma(const u16* __restrict__ A,
                                                 const u16* __restrict__ B,
                                                 void* __restrict__ Cout,
                                                 u16* __restrict__ kbuf,
                                                 u16* __restrict__ vT,
                                                 int M, int N, int K) {
    __shared__ u16 As[128 * 32];
    __shared__ u16 Bs[128 * 32];
    const int tid  = threadIdx.x;
    const int wave = tid >> 6, lane = tid & 63;
    const int m0 = blockIdx.y * 128, n0 = blockIdx.x * 128;
    const int wm = (wave & 1) * 64, wn = (wave >> 1) * 64;

    const int srow = wave * 32 + (lane >> 2);
    const int kch  = (lane & 3) * 8;
    const u16* gA0 = A + (size_t)(m0 + srow) * K + kch;
    const u16* gA1 = gA0 + (size_t)16 * K;
    const u16* gB0 = B + (size_t)(n0 + srow) * K + kch;
    const u16* gB1 = gB0 + (size_t)16 * K;
    u16* lA0 = &As[(wave * 32) * 32];
    u16* lA1 = &As[(wave * 32 + 16) * 32];
    u16* lB0 = &Bs[(wave * 32) * 32];
    u16* lB1 = &Bs[(wave * 32 + 16) * 32];

    floatx4 acc[4][4];
#pragma unroll
    for (int i = 0; i < 4; ++i)
#pragma unroll
        for (int j = 0; j < 4; ++j) acc[i][j] = 0.f;

    const int lrow = lane & 15;
    const int lkh  = (lane >> 4) * 8;

    for (int k0 = 0; k0 < K; k0 += 32) {
        __syncthreads();
        async_copy16(gA0 + k0, lA0);
        async_copy16(gA1 + k0, lA1);
        async_copy16(gB0 + k0, lB0);
        async_copy16(gB1 + k0, lB1);
        __syncthreads();
        bf16x8 a[4], b[4];
#pragma unroll
        for (int mi = 0; mi < 4; ++mi)
            a[mi] = *(const bf16x8*)&As[(wm + mi * 16 + lrow) * 32 + lkh];
#pragma unroll
        for (int ni = 0; ni < 4; ++ni)
            b[ni] = *(const bf16x8*)&Bs[(wn + ni * 16 + lrow) * 32 + lkh];
#pragma unroll
        for (int mi = 0; mi < 4; ++mi)
#pragma unroll
            for (int ni = 0; ni < 4; ++ni)
                acc[mi][ni] = __builtin_amdgcn_mfma_f32_16x16x32_bf16(
                    a[mi], b[ni], acc[mi][ni], 0, 0, 0);
    }

    const int crow = (lane >> 4) * 4, ccol = lane & 15;
#pragma unroll
    for (int mi = 0; mi < 4; ++mi)
#pragma unroll
        for (int ni = 0; ni < 4; ++ni) {
            const int m = m0 + wm + mi * 16 + crow;
            const int c = n0 + wn + ni * 16 + ccol;
            if (MODE == 0) {
                float* cp = (float*)Cout + (size_t)m * N + c;
#pragma unroll
                for (int r = 0; r < 4; ++r) cp[(size_t)r * N] = acc[mi][ni][r];
            } else if (MODE == 1) {
                u16* cp = (u16*)Cout + (size_t)m * N + c;
#pragma unroll
                for (int r = 0; r < 4; ++r) cp[(size_t)r * N] = f2bf(acc[mi][ni][r]);
            } else {
                const int hh = c >> 8, j = c & 255;
                const int bb = m >> 11, t = m & 2047;
                if (j < 128) {
#pragma unroll
                    for (int r = 0; r < 4; ++r)
                        kbuf[(((size_t)hh * 2 + bb) * 2048 + t + r) * 192 + j] =
                            f2bf(acc[mi][ni][r]);
                } else {
                    u16x4 pk;
#pragma unroll
                    for (int r = 0; r < 4; ++r) pk[r] = f2bf(acc[mi][ni][r]);
                    *(u16x4*)&vT[(((size_t)hh * 2 + bb) * 128 + (j - 128)) * 2048 + t] = pk;
                }
            }
        }
}

// NOTE: the reference computes q_pe = rotary(q_pe) but then uses the ORIGINAL
// (unrotated) q in the score einsum — the rotated q_pe is dead code there.
// So q gets NO RoPE; only k_pe is rotated.

// ---------------------------------------------------------------------------
// Per-token: rmsnorm(kv_c)*w -> kvn_bf; rotary(k_pe) -> kbuf[h][b][t][128..191].
// ---------------------------------------------------------------------------
__global__ __launch_bounds__(256) void kv_fix(const float* __restrict__ kv_raw,
                                              const float* __restrict__ w,
                                              const float* __restrict__ fcos,
                                              const float* __restrict__ fsin,
                                              u16* __restrict__ kvn_bf,
                                              u16* __restrict__ kbuf) {
    const int row = blockIdx.x;
    const int tid = threadIdx.x;
    const float* src = kv_raw + (size_t)row * 640;
    const float v0 = src[tid];
    const float v1 = src[256 + tid];
    float ss = v0 * v0 + v1 * v1;
#pragma unroll
    for (int off = 32; off > 0; off >>= 1) ss += __shfl_down(ss, off, 64);
    __shared__ float red[4];
    __shared__ float kpe_s[64];
    if ((tid & 63) == 0) red[tid >> 6] = ss;
    if (tid < 32) {
        const int s = row & (SEQ - 1);
        const float c  = fcos[s * 32 + tid];
        const float sn = fsin[s * 32 + tid];
        const float xr = src[KV_LORA + 2 * tid];
        const float xi = src[KV_LORA + 2 * tid + 1];
        kpe_s[2 * tid]     = xr * c - xi * sn;
        kpe_s[2 * tid + 1] = xr * sn + xi * c;
    }
    __syncthreads();
    const float tot = red[0] + red[1] + red[2] + red[3];
    const float inv = rsqrtf(tot * (1.0f / KV_LORA) + EPSF);
    kvn_bf[(size_t)row * KV_LORA + tid]       = f2bf(v0 * inv * w[tid]);
    kvn_bf[(size_t)row * KV_LORA + 256 + tid] = f2bf(v1 * inv * w[256 + tid]);
    const int bb = row >> 11, t = row & 2047;
    const int hh = tid >> 4, dg = (tid & 15) * 4;
    u16x4 pk;
#pragma unroll
    for (int j = 0; j < 4; ++j) pk[j] = f2bf(kpe_s[dg + j]);
    *(u16x4*)&kbuf[(((size_t)hh * 2 + bb) * 2048 + t) * 192 + 128 + dg] = pk;
}

// ---------------------------------------------------------------------------
// MFMA flash attention v2: 128 q-rows/block, 32 q/wave (2 groups of 16),
// 64-token K/V tile. Each K/V LDS fragment feeds 2 MFMAs (one per q-group):
// per wave-iter 80 MFMA vs ~48 ds_read_b128 (was 40:42 in v1).
// q-tiles launched DESCENDING so longest causal blocks start first.
// LDS: Ks 24KB + Vs 16KB + Ps[4][32][72] 18KB = 58KB -> 2 blocks/CU.
// ---------------------------------------------------------------------------
__global__ __launch_bounds__(256, 2) void attn_mfma(const u16* __restrict__ qbf,
                                                    const u16* __restrict__ kbuf,
                                                    const u16* __restrict__ vT,
                                                    u16* __restrict__ att,
                                                    float scale) {
    __shared__ __attribute__((aligned(16))) u16 Ks[6 * 64 * 32];
    __shared__ __attribute__((aligned(16))) u16 Vs[2 * 128 * 32];
    __shared__ __attribute__((aligned(16))) u16 Ps[4][32 * 72];
    const int qt = (gridDim.x - 1) - blockIdx.x;   // descending work order
    const int h = blockIdx.y, b = blockIdx.z;
    const int tid = threadIdx.x, wave = tid >> 6, lane = tid & 63;
    const int l15 = lane & 15, lg = lane >> 4;

    // Q B-frags for this wave's 2 q-groups (rows g*64 + wave*16 + l15)
    int qrow[2];
    bf16x8 qf[2][6];
#pragma unroll
    for (int g = 0; g < 2; ++g) {
        qrow[g] = qt * 128 + g * 64 + wave * 16 + l15;   // seq-local
        const size_t qoff = ((size_t)(b * SEQ + qrow[g])) * QROW + h * 192 + lg * 8;
#pragma unroll
        for (int s = 0; s < 6; ++s) qf[g][s] = *(const bf16x8*)&qbf[qoff + s * 32];
    }

    const u16* kb_base = kbuf + ((size_t)(h * 2 + b)) * 2048 * 192;
    const u16* vt_base = vT   + ((size_t)(h * 2 + b)) * 128 * 2048;

    floatx4 oacc[2][8];
#pragma unroll
    for (int g = 0; g < 2; ++g)
#pragma unroll
        for (int v = 0; v < 8; ++v) oacc[g][v] = 0.f;
    float m_run[2] = {-1e30f, -1e30f}, l_run[2] = {0.f, 0.f};

    const int kt_max = 2 * qt + 1;
    for (int kt = 0; kt <= kt_max; ++kt) {
        const int t0 = kt * 64;
        __syncthreads();
        // stage K tile [64][192] -> Ks[s][t][32]; 6 calls per wave
#pragma unroll
        for (int i = 0; i < 6; ++i) {
            const int base = (wave * 6 + i) * 64;
            const int slot = base + lane;
            const int s = slot >> 8, r = slot & 255, tk = r >> 2, ch = r & 3;
            async_copy16(kb_base + ((size_t)(t0 + tk)) * 192 + s * 32 + ch * 8,
                         &Ks[base * 8]);
        }
        // stage V^T tile [128][64] -> Vs[s][v][32]; 4 calls per wave
#pragma unroll
        for (int i = 0; i < 4; ++i) {
            const int base = (wave * 4 + i) * 64;
            const int slot = base + lane;
            const int s = slot >> 9, r = slot & 511, v = r >> 2, ch = r & 3;
            async_copy16(vt_base + ((size_t)v) * 2048 + t0 + s * 32 + ch * 8,
                         &Vs[base * 8]);
        }
        __syncthreads();
        // S^T[64t][16q] per group: share each K frag across both q-groups
        floatx4 sacc[2][4];
#pragma unroll
        for (int g = 0; g < 2; ++g)
#pragma unroll
            for (int mt = 0; mt < 4; ++mt) sacc[g][mt] = 0.f;
#pragma unroll
        for (int s = 0; s < 6; ++s) {
#pragma unroll
            for (int mt = 0; mt < 4; ++mt) {
                const bf16x8 kf = *(const bf16x8*)&Ks[(s * 64 + mt * 16 + l15) * 32 + lg * 8];
#pragma unroll
                for (int g = 0; g < 2; ++g)
                    sacc[g][mt] = __builtin_amdgcn_mfma_f32_16x16x32_bf16(
                        kf, qf[g][s], sacc[g][mt], 0, 0, 0);
            }
        }
        // online softmax per q-col (lane's q for group g = qrow[g])
        float alpha[2];
#pragma unroll
        for (int g = 0; g < 2; ++g) {
            float p[16];
            float tmax = -1e30f;
#pragma unroll
            for (int mt = 0; mt < 4; ++mt)
#pragma unroll
                for (int r = 0; r < 4; ++r) {
                    const int tglob = t0 + mt * 16 + lg * 4 + r;
                    float v = sacc[g][mt][r] * scale;
                    v = (tglob <= qrow[g]) ? v : -1e30f;
                    p[mt * 4 + r] = v;
                    tmax = fmaxf(tmax, v);
                }
            tmax = fmaxf(tmax, __shfl_xor(tmax, 16));
            tmax = fmaxf(tmax, __shfl_xor(tmax, 32));
            const float mnew = fmaxf(m_run[g], tmax);
            alpha[g] = __expf(m_run[g] - mnew);
            m_run[g] = mnew;
            float rsum = 0.f;
#pragma unroll
            for (int k = 0; k < 16; ++k) { p[k] = __expf(p[k] - mnew); rsum += p[k]; }
            rsum += __shfl_xor(rsum, 16);
            rsum += __shfl_xor(rsum, 32);
            l_run[g] = l_run[g] * alpha[g] + rsum;
#pragma unroll
            for (int mt = 0; mt < 4; ++mt) {
                u16x4 pk;
#pragma unroll
                for (int r = 0; r < 4; ++r) pk[r] = f2bf(p[mt * 4 + r]);
                *(u16x4*)&Ps[wave][(g * 16 + l15) * 72 + mt * 16 + lg * 4] = pk;
            }
        }
        // rescale O by alpha per q-row (broadcast from lane owning that q)
#pragma unroll
        for (int g = 0; g < 2; ++g) {
            float af[4];
#pragma unroll
            for (int r = 0; r < 4; ++r) af[r] = __shfl(alpha[g], lg * 4 + r);
#pragma unroll
            for (int vt = 0; vt < 8; ++vt)
#pragma unroll
                for (int r = 0; r < 4; ++r) oacc[g][vt][r] *= af[r];
        }
        // O[g][16q][128v] += P @ V : share each V frag across both q-groups
#pragma unroll
        for (int s = 0; s < 2; ++s) {
            bf16x8 pf[2];
#pragma unroll
            for (int g = 0; g < 2; ++g)
                pf[g] = *(const bf16x8*)&Ps[wave][(g * 16 + l15) * 72 + s * 32 + lg * 8];
#pragma unroll
            for (int vt = 0; vt < 8; ++vt) {
                const bf16x8 vf = *(const bf16x8*)&Vs[(s * 128 + vt * 16 + l15) * 32 + lg * 8];
#pragma unroll
                for (int g = 0; g < 2; ++g)
                    oacc[g][vt] = __builtin_amdgcn_mfma_f32_16x16x32_bf16(
                        pf[g], vf, oacc[g][vt], 0, 0, 0);
            }
        }
    }
    // epilogue: divide by l, store bf16
#pragma unroll
    for (int g = 0; g < 2; ++g) {
        float lf[4];
#pragma unroll
        for (int r = 0; r < 4; ++r) lf[r] = 1.0f / __shfl(l_run[g], lg * 4 + r);
#pragma unroll
        for (int vt = 0; vt < 8; ++vt)
#pragma unroll
            for (int r = 0; r < 4; ++r) {
                const int orow = b * SEQ + qt * 128 + g * 64 + wave * 16 + lg * 4 + r;
                att[(size_t)orow * 2048 + h * 128 + vt * 16 + l15] =
                    f2bf(oacc[g][vt][r] * lf[r]);
            }
    }
}

// ---------------------------------------------------------------------------
extern "C" void kernel_launch(void* const* d_in, const int* in_sizes, int n_in,
                              void* d_out, int out_size, void* d_ws, size_t ws_size,
                              hipStream_t stream) {
    const float* x     = (const float*)d_in[0];
    const float* wq    = (const float*)d_in[1];
    const float* wkv_a = (const float*)d_in[2];
    const float* knw   = (const float*)d_in[3];
    const float* wkv_b = (const float*)d_in[4];
    const float* wo    = (const float*)d_in[5];
    const float* fcos  = (const float*)d_in[6];
    const float* fsin  = (const float*)d_in[7];
    float* out = (float*)d_out;

    char* w = (char*)d_ws;
    u16*   x_bf    = (u16*)w;  w += (size_t)NTOK * 2048 * 2;
    u16*   wq_bf   = (u16*)w;  w += (size_t)QROW * 2048 * 2;
    u16*   wkva_bf = (u16*)w;  w += (size_t)640 * 2048 * 2;
    u16*   wkvb_bf = (u16*)w;  w += (size_t)KVBROW * KV_LORA * 2;
    u16*   wo_bf   = (u16*)w;  w += (size_t)2048 * 2048 * 2;
    u16*   q_bf    = (u16*)w;  w += (size_t)NTOK * QROW * 2;
    float* kv_raw  = (float*)w; w += (size_t)NTOK * 640 * 4;
    u16*   kvn_bf  = (u16*)w;  w += (size_t)NTOK * KV_LORA * 2;
    u16*   kbuf    = (u16*)w;  w += (size_t)NH * NB * SEQ * 192 * 2;
    u16*   vT      = (u16*)w;  w += (size_t)NH * NB * 128 * SEQ * 2;
    u16*   att_bf  = (u16*)w;  w += (size_t)NTOK * 2048 * 2;

    const double mm = 0.1 * 1.0 * log(40.0) + 1.0;
    const float scale = (float)((1.0 / sqrt((double)D_QK)) * mm * mm);

    dim3 blk(256);
    cast_bf16<<<dim3(NTOK * 2048 / 1024), blk, 0, stream>>>(x, x_bf);
    cast_bf16<<<dim3(QROW * 2048 / 1024), blk, 0, stream>>>(wq, wq_bf);
    cast_pad_wkva<<<dim3(640 * 2048 / 1024), blk, 0, stream>>>(wkv_a, wkva_bf);
    cast_bf16<<<dim3(KVBROW * KV_LORA / 1024), blk, 0, stream>>>(wkv_b, wkvb_bf);
    cast_bf16<<<dim3(2048 * 2048 / 1024), blk, 0, stream>>>(wo, wo_bf);
    gemm_mfma<1><<<dim3(QROW / 128, NTOK / 128), blk, 0, stream>>>(
        x_bf, wq_bf, q_bf, nullptr, nullptr, NTOK, QROW, 2048);
    gemm_mfma<0><<<dim3(640 / 128, NTOK / 128), blk, 0, stream>>>(
        x_bf, wkva_bf, kv_raw, nullptr, nullptr, NTOK, 640, 2048);
    kv_fix<<<dim3(NTOK), blk, 0, stream>>>(kv_raw, knw, fcos, fsin, kvn_bf, kbuf);
    gemm_mfma<2><<<dim3(KVBROW / 128, NTOK / 128), blk, 0, stream>>>(
        kvn_bf, wkvb_bf, nullptr, kbuf, vT, NTOK, KVBROW, KV_LORA);
    attn_mfma<<<dim3(SEQ / 128, NH, NB), blk, 0, stream>>>(q_bf, kbuf, vT, att_bf, scale);
    gemm_mfma<0><<<dim3(2048 / 128, NTOK / 128), blk, 0, stream>>>(
        att_bf, wo_bf, out, nullptr, nullptr, NTOK, 2048, 2048);
}

// Round 6
// 456.333 us; speedup vs baseline: 7.2472x; 1.0432x over previous
//
#include <hip/hip_runtime.h>
#include <math.h>

#define NH      16
#define D_NOPE  128
#define D_ROPE  64
#define D_QK    192
#define D_V     128
#define KV_LORA 512
#define NB      2
#define SEQ     2048
#define NTOK    (NB*SEQ)          // 4096
#define QROW    (NH*D_QK)         // 3072
#define KVBROW  (NH*(D_NOPE+D_V)) // 4096
#define EPSF    1e-6f

typedef unsigned short u16;
typedef float  floatx4 __attribute__((ext_vector_type(4)));
typedef __bf16 bf16x8  __attribute__((ext_vector_type(8)));
typedef u16    u16x4   __attribute__((ext_vector_type(4)));
typedef u16    u16x8   __attribute__((ext_vector_type(8)));

__device__ __forceinline__ u16 f2bf(float f) {
    unsigned u = __builtin_bit_cast(unsigned, f);
    return (u16)((u + 0x7fffu + ((u >> 16) & 1u)) >> 16);
}

__device__ __forceinline__ void async_copy16(const void* g, void* l) {
    __builtin_amdgcn_global_load_lds(
        (const __attribute__((address_space(1))) unsigned int*)g,
        (__attribute__((address_space(3))) unsigned int*)l,
        16, 0, 0);
}

// ---------------------------------------------------------------------------
// Fused fp32->bf16 cast of all 5 weight/activation arrays in ONE dispatch.
// Segment boundaries in 1024-element blocks:
//   x: 8192 | wq: 6144 | wkva(pad 576->640 rows): 1280 | wkvb: 2048 | wo: 4096
// ---------------------------------------------------------------------------
__global__ __launch_bounds__(256) void cast_all(const float* __restrict__ x,
                                                const float* __restrict__ wq,
                                                const float* __restrict__ wkva,
                                                const float* __restrict__ wkvb,
                                                const float* __restrict__ wo,
                                                u16* __restrict__ xb,
                                                u16* __restrict__ wqb,
                                                u16* __restrict__ wkvab,
                                                u16* __restrict__ wkvbb,
                                                u16* __restrict__ wob) {
    int blk = blockIdx.x;
    const float* src; u16* dst; bool pad = false;
    if (blk < 8192)        { src = x;    dst = xb; }
    else if (blk < 14336)  { blk -= 8192;  src = wq;   dst = wqb; }
    else if (blk < 15616)  { blk -= 14336; src = wkva; dst = wkvab; pad = true; }
    else if (blk < 17664)  { blk -= 15616; src = wkvb; dst = wkvbb; }
    else                   { blk -= 17664; src = wo;   dst = wob; }
    const int i = (blk * 256 + threadIdx.x) * 4;
    u16x4 o;
    if (pad && (i >> 11) >= 576) {
        o[0] = 0; o[1] = 0; o[2] = 0; o[3] = 0;
    } else {
        const float4 v = *(const float4*)&src[i];
        o[0] = f2bf(v.x); o[1] = f2bf(v.y); o[2] = f2bf(v.z); o[3] = f2bf(v.w);
    }
    *(u16x4*)&dst[i] = o;
}

// ---------------------------------------------------------------------------
// bf16 NT MFMA GEMM (m97 recipe), templated epilogue:
//   MODE 0: fp32 C[M,N]
//   MODE 1: bf16 C[M,N]
//   MODE 2: kv-split: cols j<128 of each head's 256 -> kbuf (k_nope),
//           cols j>=128 -> vT (transposed V), both bf16.
// ---------------------------------------------------------------------------
template<int MODE>
__global__ __launch_bounds__(256) void gemm_mfma(const u16* __restrict__ A,
                                                 const u16* __restrict__ B,
                                                 void* __restrict__ Cout,
                                                 u16* __restrict__ kbuf,
                                                 u16* __restrict__ vT,
                                                 int M, int N, int K) {
    __shared__ u16 As[128 * 32];
    __shared__ u16 Bs[128 * 32];
    const int tid  = threadIdx.x;
    const int wave = tid >> 6, lane = tid & 63;
    const int m0 = blockIdx.y * 128, n0 = blockIdx.x * 128;
    const int wm = (wave & 1) * 64, wn = (wave >> 1) * 64;

    const int srow = wave * 32 + (lane >> 2);
    const int kch  = (lane & 3) * 8;
    const u16* gA0 = A + (size_t)(m0 + srow) * K + kch;
    const u16* gA1 = gA0 + (size_t)16 * K;
    const u16* gB0 = B + (size_t)(n0 + srow) * K + kch;
    const u16* gB1 = gB0 + (size_t)16 * K;
    u16* lA0 = &As[(wave * 32) * 32];
    u16* lA1 = &As[(wave * 32 + 16) * 32];
    u16* lB0 = &Bs[(wave * 32) * 32];
    u16* lB1 = &Bs[(wave * 32 + 16) * 32];

    floatx4 acc[4][4];
#pragma unroll
    for (int i = 0; i < 4; ++i)
#pragma unroll
        for (int j = 0; j < 4; ++j) acc[i][j] = 0.f;

    const int lrow = lane & 15;
    const int lkh  = (lane >> 4) * 8;

    for (int k0 = 0; k0 < K; k0 += 32) {
        __syncthreads();
        async_copy16(gA0 + k0, lA0);
        async_copy16(gA1 + k0, lA1);
        async_copy16(gB0 + k0, lB0);
        async_copy16(gB1 + k0, lB1);
        __syncthreads();
        bf16x8 a[4], b[4];
#pragma unroll
        for (int mi = 0; mi < 4; ++mi)
            a[mi] = *(const bf16x8*)&As[(wm + mi * 16 + lrow) * 32 + lkh];
#pragma unroll
        for (int ni = 0; ni < 4; ++ni)
            b[ni] = *(const bf16x8*)&Bs[(wn + ni * 16 + lrow) * 32 + lkh];
#pragma unroll
        for (int mi = 0; mi < 4; ++mi)
#pragma unroll
            for (int ni = 0; ni < 4; ++ni)
                acc[mi][ni] = __builtin_amdgcn_mfma_f32_16x16x32_bf16(
                    a[mi], b[ni], acc[mi][ni], 0, 0, 0);
    }

    const int crow = (lane >> 4) * 4, ccol = lane & 15;
#pragma unroll
    for (int mi = 0; mi < 4; ++mi)
#pragma unroll
        for (int ni = 0; ni < 4; ++ni) {
            const int m = m0 + wm + mi * 16 + crow;
            const int c = n0 + wn + ni * 16 + ccol;
            if (MODE == 0) {
                float* cp = (float*)Cout + (size_t)m * N + c;
#pragma unroll
                for (int r = 0; r < 4; ++r) cp[(size_t)r * N] = acc[mi][ni][r];
            } else if (MODE == 1) {
                u16* cp = (u16*)Cout + (size_t)m * N + c;
#pragma unroll
                for (int r = 0; r < 4; ++r) cp[(size_t)r * N] = f2bf(acc[mi][ni][r]);
            } else {
                const int hh = c >> 8, j = c & 255;
                const int bb = m >> 11, t = m & 2047;
                if (j < 128) {
#pragma unroll
                    for (int r = 0; r < 4; ++r)
                        kbuf[(((size_t)hh * 2 + bb) * 2048 + t + r) * 192 + j] =
                            f2bf(acc[mi][ni][r]);
                } else {
                    u16x4 pk;
#pragma unroll
                    for (int r = 0; r < 4; ++r) pk[r] = f2bf(acc[mi][ni][r]);
                    *(u16x4*)&vT[(((size_t)hh * 2 + bb) * 128 + (j - 128)) * 2048 + t] = pk;
                }
            }
        }
}

// NOTE: the reference computes q_pe = rotary(q_pe) but then uses the ORIGINAL
// (unrotated) q in the score einsum — the rotated q_pe is dead code there.
// So q gets NO RoPE; only k_pe is rotated.

// ---------------------------------------------------------------------------
// Per-token: rmsnorm(kv_c)*w -> kvn_bf; rotary(k_pe) -> kbuf[h][b][t][128..191].
// ---------------------------------------------------------------------------
__global__ __launch_bounds__(256) void kv_fix(const float* __restrict__ kv_raw,
                                              const float* __restrict__ w,
                                              const float* __restrict__ fcos,
                                              const float* __restrict__ fsin,
                                              u16* __restrict__ kvn_bf,
                                              u16* __restrict__ kbuf) {
    const int row = blockIdx.x;
    const int tid = threadIdx.x;
    const float* src = kv_raw + (size_t)row * 640;
    const float v0 = src[tid];
    const float v1 = src[256 + tid];
    float ss = v0 * v0 + v1 * v1;
#pragma unroll
    for (int off = 32; off > 0; off >>= 1) ss += __shfl_down(ss, off, 64);
    __shared__ float red[4];
    __shared__ float kpe_s[64];
    if ((tid & 63) == 0) red[tid >> 6] = ss;
    if (tid < 32) {
        const int s = row & (SEQ - 1);
        const float c  = fcos[s * 32 + tid];
        const float sn = fsin[s * 32 + tid];
        const float xr = src[KV_LORA + 2 * tid];
        const float xi = src[KV_LORA + 2 * tid + 1];
        kpe_s[2 * tid]     = xr * c - xi * sn;
        kpe_s[2 * tid + 1] = xr * sn + xi * c;
    }
    __syncthreads();
    const float tot = red[0] + red[1] + red[2] + red[3];
    const float inv = rsqrtf(tot * (1.0f / KV_LORA) + EPSF);
    kvn_bf[(size_t)row * KV_LORA + tid]       = f2bf(v0 * inv * w[tid]);
    kvn_bf[(size_t)row * KV_LORA + 256 + tid] = f2bf(v1 * inv * w[256 + tid]);
    const int bb = row >> 11, t = row & 2047;
    const int hh = tid >> 4, dg = (tid & 15) * 4;
    u16x4 pk;
#pragma unroll
    for (int j = 0; j < 4; ++j) pk[j] = f2bf(kpe_s[dg + j]);
    *(u16x4*)&kbuf[(((size_t)hh * 2 + bb) * 2048 + t) * 192 + 128 + dg] = pk;
}

// ---------------------------------------------------------------------------
// MFMA flash attention v3: triangle-paired q-tiles for perfect causal balance.
// Block qt0 in [0,8) processes q-tiles {15-qt0, qt0} sequentially (2 passes);
// total k-iterations = (2(15-qt0)+2) + (2qt0+2) = 34 for EVERY block.
// Grid = 8 x NH x NB = 256 blocks = 1/CU, all CUs busy to the end.
// Per pass: 128 q-rows, 32 q/wave (2 groups of 16), 64-token K/V tiles;
// each K/V LDS fragment feeds 2 MFMAs. Mask VALU only on diagonal tiles.
// LDS: Ks 24KB + Vs 16KB + Ps[4][32][72] 18KB = 58KB.
// ---------------------------------------------------------------------------
__global__ __launch_bounds__(256, 2) void attn_mfma(const u16* __restrict__ qbf,
                                                    const u16* __restrict__ kbuf,
                                                    const u16* __restrict__ vT,
                                                    u16* __restrict__ att,
                                                    float scale) {
    __shared__ __attribute__((aligned(16))) u16 Ks[6 * 64 * 32];
    __shared__ __attribute__((aligned(16))) u16 Vs[2 * 128 * 32];
    __shared__ __attribute__((aligned(16))) u16 Ps[4][32 * 72];
    const int qt0 = blockIdx.x;                    // 0..7
    const int h = blockIdx.y, b = blockIdx.z;
    const int tid = threadIdx.x, wave = tid >> 6, lane = tid & 63;
    const int l15 = lane & 15, lg = lane >> 4;

    const u16* kb_base = kbuf + ((size_t)(h * 2 + b)) * 2048 * 192;
    const u16* vt_base = vT   + ((size_t)(h * 2 + b)) * 128 * 2048;

    for (int pass = 0; pass < 2; ++pass) {
        const int qt = pass ? qt0 : (15 - qt0);    // heavy tile first

        // Q B-frags for this wave's 2 q-groups
        int qrow[2];
        bf16x8 qf[2][6];
#pragma unroll
        for (int g = 0; g < 2; ++g) {
            qrow[g] = qt * 128 + g * 64 + wave * 16 + l15;
            const size_t qoff = ((size_t)(b * SEQ + qrow[g])) * QROW + h * 192 + lg * 8;
#pragma unroll
            for (int s = 0; s < 6; ++s) qf[g][s] = *(const bf16x8*)&qbf[qoff + s * 32];
        }

        floatx4 oacc[2][8];
#pragma unroll
        for (int g = 0; g < 2; ++g)
#pragma unroll
            for (int v = 0; v < 8; ++v) oacc[g][v] = 0.f;
        float m_run[2] = {-1e30f, -1e30f}, l_run[2] = {0.f, 0.f};

        const int kt_max = 2 * qt + 1;
        for (int kt = 0; kt <= kt_max; ++kt) {
            const int t0 = kt * 64;
            __syncthreads();
            // stage K tile [64][192] -> Ks[s][t][32]; 6 calls per wave
#pragma unroll
            for (int i = 0; i < 6; ++i) {
                const int base = (wave * 6 + i) * 64;
                const int slot = base + lane;
                const int s = slot >> 8, r = slot & 255, tk = r >> 2, ch = r & 3;
                async_copy16(kb_base + ((size_t)(t0 + tk)) * 192 + s * 32 + ch * 8,
                             &Ks[base * 8]);
            }
            // stage V^T tile [128][64] -> Vs[s][v][32]; 4 calls per wave
#pragma unroll
            for (int i = 0; i < 4; ++i) {
                const int base = (wave * 4 + i) * 64;
                const int slot = base + lane;
                const int s = slot >> 9, r = slot & 511, v = r >> 2, ch = r & 3;
                async_copy16(vt_base + ((size_t)v) * 2048 + t0 + s * 32 + ch * 8,
                             &Vs[base * 8]);
            }
            __syncthreads();
            // S^T[64t][16q] per group: share each K frag across both q-groups
            floatx4 sacc[2][4];
#pragma unroll
            for (int g = 0; g < 2; ++g)
#pragma unroll
                for (int mt = 0; mt < 4; ++mt) sacc[g][mt] = 0.f;
#pragma unroll
            for (int s = 0; s < 6; ++s) {
#pragma unroll
                for (int mt = 0; mt < 4; ++mt) {
                    const bf16x8 kf = *(const bf16x8*)&Ks[(s * 64 + mt * 16 + l15) * 32 + lg * 8];
#pragma unroll
                    for (int g = 0; g < 2; ++g)
                        sacc[g][mt] = __builtin_amdgcn_mfma_f32_16x16x32_bf16(
                            kf, qf[g][s], sacc[g][mt], 0, 0, 0);
                }
            }
            // online softmax per q-col
            float alpha[2];
#pragma unroll
            for (int g = 0; g < 2; ++g) {
                // tile fully visible for every lane of this wave's group g?
                const bool full = (t0 + 63) <= (qt * 128 + g * 64 + wave * 16);
                float p[16];
                float tmax = -1e30f;
#pragma unroll
                for (int mt = 0; mt < 4; ++mt)
#pragma unroll
                    for (int r = 0; r < 4; ++r) {
                        float v = sacc[g][mt][r] * scale;
                        if (!full) {
                            const int tglob = t0 + mt * 16 + lg * 4 + r;
                            v = (tglob <= qrow[g]) ? v : -1e30f;
                        }
                        p[mt * 4 + r] = v;
                        tmax = fmaxf(tmax, v);
                    }
                tmax = fmaxf(tmax, __shfl_xor(tmax, 16));
                tmax = fmaxf(tmax, __shfl_xor(tmax, 32));
                const float mnew = fmaxf(m_run[g], tmax);
                alpha[g] = __expf(m_run[g] - mnew);
                m_run[g] = mnew;
                float rsum = 0.f;
#pragma unroll
                for (int k = 0; k < 16; ++k) { p[k] = __expf(p[k] - mnew); rsum += p[k]; }
                rsum += __shfl_xor(rsum, 16);
                rsum += __shfl_xor(rsum, 32);
                l_run[g] = l_run[g] * alpha[g] + rsum;
#pragma unroll
                for (int mt = 0; mt < 4; ++mt) {
                    u16x4 pk;
#pragma unroll
                    for (int r = 0; r < 4; ++r) pk[r] = f2bf(p[mt * 4 + r]);
                    *(u16x4*)&Ps[wave][(g * 16 + l15) * 72 + mt * 16 + lg * 4] = pk;
                }
            }
            // rescale O by alpha per q-row
#pragma unroll
            for (int g = 0; g < 2; ++g) {
                float af[4];
#pragma unroll
                for (int r = 0; r < 4; ++r) af[r] = __shfl(alpha[g], lg * 4 + r);
#pragma unroll
                for (int vt = 0; vt < 8; ++vt)
#pragma unroll
                    for (int r = 0; r < 4; ++r) oacc[g][vt][r] *= af[r];
            }
            // O[g][16q][128v] += P @ V
#pragma unroll
            for (int s = 0; s < 2; ++s) {
                bf16x8 pf[2];
#pragma unroll
                for (int g = 0; g < 2; ++g)
                    pf[g] = *(const bf16x8*)&Ps[wave][(g * 16 + l15) * 72 + s * 32 + lg * 8];
#pragma unroll
                for (int vt = 0; vt < 8; ++vt) {
                    const bf16x8 vf = *(const bf16x8*)&Vs[(s * 128 + vt * 16 + l15) * 32 + lg * 8];
#pragma unroll
                    for (int g = 0; g < 2; ++g)
                        oacc[g][vt] = __builtin_amdgcn_mfma_f32_16x16x32_bf16(
                            pf[g], vf, oacc[g][vt], 0, 0, 0);
                }
            }
        }
        // epilogue: divide by l, store bf16
#pragma unroll
        for (int g = 0; g < 2; ++g) {
            float lf[4];
#pragma unroll
            for (int r = 0; r < 4; ++r) lf[r] = 1.0f / __shfl(l_run[g], lg * 4 + r);
#pragma unroll
            for (int vt = 0; vt < 8; ++vt)
#pragma unroll
                for (int r = 0; r < 4; ++r) {
                    const int orow = b * SEQ + qt * 128 + g * 64 + wave * 16 + lg * 4 + r;
                    att[(size_t)orow * 2048 + h * 128 + vt * 16 + l15] =
                        f2bf(oacc[g][vt][r] * lf[r]);
                }
        }
        __syncthreads();   // Ks/Vs/Ps reuse safety across passes
    }
}

// ---------------------------------------------------------------------------
extern "C" void kernel_launch(void* const* d_in, const int* in_sizes, int n_in,
                              void* d_out, int out_size, void* d_ws, size_t ws_size,
                              hipStream_t stream) {
    const float* x     = (const float*)d_in[0];
    const float* wq    = (const float*)d_in[1];
    const float* wkv_a = (const float*)d_in[2];
    const float* knw   = (const float*)d_in[3];
    const float* wkv_b = (const float*)d_in[4];
    const float* wo    = (const float*)d_in[5];
    const float* fcos  = (const float*)d_in[6];
    const float* fsin  = (const float*)d_in[7];
    float* out = (float*)d_out;

    char* w = (char*)d_ws;
    u16*   x_bf    = (u16*)w;  w += (size_t)NTOK * 2048 * 2;
    u16*   wq_bf   = (u16*)w;  w += (size_t)QROW * 2048 * 2;
    u16*   wkva_bf = (u16*)w;  w += (size_t)640 * 2048 * 2;
    u16*   wkvb_bf = (u16*)w;  w += (size_t)KVBROW * KV_LORA * 2;
    u16*   wo_bf   = (u16*)w;  w += (size_t)2048 * 2048 * 2;
    u16*   q_bf    = (u16*)w;  w += (size_t)NTOK * QROW * 2;
    float* kv_raw  = (float*)w; w += (size_t)NTOK * 640 * 4;
    u16*   kvn_bf  = (u16*)w;  w += (size_t)NTOK * KV_LORA * 2;
    u16*   kbuf    = (u16*)w;  w += (size_t)NH * NB * SEQ * 192 * 2;
    u16*   vT      = (u16*)w;  w += (size_t)NH * NB * 128 * SEQ * 2;
    u16*   att_bf  = (u16*)w;  w += (size_t)NTOK * 2048 * 2;

    const double mm = 0.1 * 1.0 * log(40.0) + 1.0;
    const float scale = (float)((1.0 / sqrt((double)D_QK)) * mm * mm);

    dim3 blk(256);
    cast_all<<<dim3(21760), blk, 0, stream>>>(x, wq, wkv_a, wkv_b, wo,
                                              x_bf, wq_bf, wkva_bf, wkvb_bf, wo_bf);
    gemm_mfma<1><<<dim3(QROW / 128, NTOK / 128), blk, 0, stream>>>(
        x_bf, wq_bf, q_bf, nullptr, nullptr, NTOK, QROW, 2048);
    gemm_mfma<0><<<dim3(640 / 128, NTOK / 128), blk, 0, stream>>>(
        x_bf, wkva_bf, kv_raw, nullptr, nullptr, NTOK, 640, 2048);
    kv_fix<<<dim3(NTOK), blk, 0, stream>>>(kv_raw, knw, fcos, fsin, kvn_bf, kbuf);
    gemm_mfma<2><<<dim3(KVBROW / 128, NTOK / 128), blk, 0, stream>>>(
        kvn_bf, wkvb_bf, nullptr, kbuf, vT, NTOK, KVBROW, KV_LORA);
    attn_mfma<<<dim3(SEQ / 256, NH, NB), blk, 0, stream>>>(q_bf, kbuf, vT, att_bf, scale);
    gemm_mfma<0><<<dim3(2048 / 128, NTOK / 128), blk, 0, stream>>>(
        att_bf, wo_bf, out, nullptr, nullptr, NTOK, 2048, 2048);
}

// Round 7
// 435.231 us; speedup vs baseline: 7.5986x; 1.0485x over previous
//
#include <hip/hip_runtime.h>
#include <math.h>

#define NH      16
#define D_NOPE  128
#define D_ROPE  64
#define D_QK    192
#define D_V     128
#define KV_LORA 512
#define NB      2
#define SEQ     2048
#define NTOK    (NB*SEQ)          // 4096
#define QROW    (NH*D_QK)         // 3072
#define KVBROW  (NH*(D_NOPE+D_V)) // 4096
#define EPSF    1e-6f

typedef unsigned short u16;
typedef float  floatx4 __attribute__((ext_vector_type(4)));
typedef __bf16 bf16x8  __attribute__((ext_vector_type(8)));
typedef u16    u16x4   __attribute__((ext_vector_type(4)));
typedef u16    u16x8   __attribute__((ext_vector_type(8)));

__device__ __forceinline__ u16 f2bf(float f) {
    unsigned u = __builtin_bit_cast(unsigned, f);
    return (u16)((u + 0x7fffu + ((u >> 16) & 1u)) >> 16);
}

__device__ __forceinline__ void async_copy16(const void* g, void* l) {
    __builtin_amdgcn_global_load_lds(
        (const __attribute__((address_space(1))) unsigned int*)g,
        (__attribute__((address_space(3))) unsigned int*)l,
        16, 0, 0);
}

// ---------------------------------------------------------------------------
// Fused fp32->bf16 cast of all 5 weight/activation arrays in ONE dispatch.
// ---------------------------------------------------------------------------
__global__ __launch_bounds__(256) void cast_all(const float* __restrict__ x,
                                                const float* __restrict__ wq,
                                                const float* __restrict__ wkva,
                                                const float* __restrict__ wkvb,
                                                const float* __restrict__ wo,
                                                u16* __restrict__ xb,
                                                u16* __restrict__ wqb,
                                                u16* __restrict__ wkvab,
                                                u16* __restrict__ wkvbb,
                                                u16* __restrict__ wob) {
    int blk = blockIdx.x;
    const float* src; u16* dst; bool pad = false;
    if (blk < 8192)        { src = x;    dst = xb; }
    else if (blk < 14336)  { blk -= 8192;  src = wq;   dst = wqb; }
    else if (blk < 15616)  { blk -= 14336; src = wkva; dst = wkvab; pad = true; }
    else if (blk < 17664)  { blk -= 15616; src = wkvb; dst = wkvbb; }
    else                   { blk -= 17664; src = wo;   dst = wob; }
    const int i = (blk * 256 + threadIdx.x) * 4;
    u16x4 o;
    if (pad && (i >> 11) >= 576) {
        o[0] = 0; o[1] = 0; o[2] = 0; o[3] = 0;
    } else {
        const float4 v = *(const float4*)&src[i];
        o[0] = f2bf(v.x); o[1] = f2bf(v.y); o[2] = f2bf(v.z); o[3] = f2bf(v.w);
    }
    *(u16x4*)&dst[i] = o;
}

// ---------------------------------------------------------------------------
// bf16 NT MFMA GEMM (m97 recipe), templated epilogue:
//   MODE 0: fp32 C[M,N] | MODE 1: bf16 C[M,N] | MODE 2: kv-split kbuf/vT.
// ---------------------------------------------------------------------------
template<int MODE>
__global__ __launch_bounds__(256) void gemm_mfma(const u16* __restrict__ A,
                                                 const u16* __restrict__ B,
                                                 void* __restrict__ Cout,
                                                 u16* __restrict__ kbuf,
                                                 u16* __restrict__ vT,
                                                 int M, int N, int K) {
    __shared__ u16 As[128 * 32];
    __shared__ u16 Bs[128 * 32];
    const int tid  = threadIdx.x;
    const int wave = tid >> 6, lane = tid & 63;
    const int m0 = blockIdx.y * 128, n0 = blockIdx.x * 128;
    const int wm = (wave & 1) * 64, wn = (wave >> 1) * 64;

    const int srow = wave * 32 + (lane >> 2);
    const int kch  = (lane & 3) * 8;
    const u16* gA0 = A + (size_t)(m0 + srow) * K + kch;
    const u16* gA1 = gA0 + (size_t)16 * K;
    const u16* gB0 = B + (size_t)(n0 + srow) * K + kch;
    const u16* gB1 = gB0 + (size_t)16 * K;
    u16* lA0 = &As[(wave * 32) * 32];
    u16* lA1 = &As[(wave * 32 + 16) * 32];
    u16* lB0 = &Bs[(wave * 32) * 32];
    u16* lB1 = &Bs[(wave * 32 + 16) * 32];

    floatx4 acc[4][4];
#pragma unroll
    for (int i = 0; i < 4; ++i)
#pragma unroll
        for (int j = 0; j < 4; ++j) acc[i][j] = 0.f;

    const int lrow = lane & 15;
    const int lkh  = (lane >> 4) * 8;

    for (int k0 = 0; k0 < K; k0 += 32) {
        __syncthreads();
        async_copy16(gA0 + k0, lA0);
        async_copy16(gA1 + k0, lA1);
        async_copy16(gB0 + k0, lB0);
        async_copy16(gB1 + k0, lB1);
        __syncthreads();
        bf16x8 a[4], b[4];
#pragma unroll
        for (int mi = 0; mi < 4; ++mi)
            a[mi] = *(const bf16x8*)&As[(wm + mi * 16 + lrow) * 32 + lkh];
#pragma unroll
        for (int ni = 0; ni < 4; ++ni)
            b[ni] = *(const bf16x8*)&Bs[(wn + ni * 16 + lrow) * 32 + lkh];
#pragma unroll
        for (int mi = 0; mi < 4; ++mi)
#pragma unroll
            for (int ni = 0; ni < 4; ++ni)
                acc[mi][ni] = __builtin_amdgcn_mfma_f32_16x16x32_bf16(
                    a[mi], b[ni], acc[mi][ni], 0, 0, 0);
    }

    const int crow = (lane >> 4) * 4, ccol = lane & 15;
#pragma unroll
    for (int mi = 0; mi < 4; ++mi)
#pragma unroll
        for (int ni = 0; ni < 4; ++ni) {
            const int m = m0 + wm + mi * 16 + crow;
            const int c = n0 + wn + ni * 16 + ccol;
            if (MODE == 0) {
                float* cp = (float*)Cout + (size_t)m * N + c;
#pragma unroll
                for (int r = 0; r < 4; ++r) cp[(size_t)r * N] = acc[mi][ni][r];
            } else if (MODE == 1) {
                u16* cp = (u16*)Cout + (size_t)m * N + c;
#pragma unroll
                for (int r = 0; r < 4; ++r) cp[(size_t)r * N] = f2bf(acc[mi][ni][r]);
            } else {
                const int hh = c >> 8, j = c & 255;
                const int bb = m >> 11, t = m & 2047;
                if (j < 128) {
#pragma unroll
                    for (int r = 0; r < 4; ++r)
                        kbuf[(((size_t)hh * 2 + bb) * 2048 + t + r) * 192 + j] =
                            f2bf(acc[mi][ni][r]);
                } else {
                    u16x4 pk;
#pragma unroll
                    for (int r = 0; r < 4; ++r) pk[r] = f2bf(acc[mi][ni][r]);
                    *(u16x4*)&vT[(((size_t)hh * 2 + bb) * 128 + (j - 128)) * 2048 + t] = pk;
                }
            }
        }
}

// NOTE: the reference computes q_pe = rotary(q_pe) but then uses the ORIGINAL
// (unrotated) q in the score einsum — the rotated q_pe is dead code there.
// So q gets NO RoPE; only k_pe is rotated.

// ---------------------------------------------------------------------------
// Per-token: rmsnorm(kv_c)*w -> kvn_bf; rotary(k_pe) -> kbuf[h][b][t][128..191].
// ---------------------------------------------------------------------------
__global__ __launch_bounds__(256) void kv_fix(const float* __restrict__ kv_raw,
                                              const float* __restrict__ w,
                                              const float* __restrict__ fcos,
                                              const float* __restrict__ fsin,
                                              u16* __restrict__ kvn_bf,
                                              u16* __restrict__ kbuf) {
    const int row = blockIdx.x;
    const int tid = threadIdx.x;
    const float* src = kv_raw + (size_t)row * 640;
    const float v0 = src[tid];
    const float v1 = src[256 + tid];
    float ss = v0 * v0 + v1 * v1;
#pragma unroll
    for (int off = 32; off > 0; off >>= 1) ss += __shfl_down(ss, off, 64);
    __shared__ float red[4];
    __shared__ float kpe_s[64];
    if ((tid & 63) == 0) red[tid >> 6] = ss;
    if (tid < 32) {
        const int s = row & (SEQ - 1);
        const float c  = fcos[s * 32 + tid];
        const float sn = fsin[s * 32 + tid];
        const float xr = src[KV_LORA + 2 * tid];
        const float xi = src[KV_LORA + 2 * tid + 1];
        kpe_s[2 * tid]     = xr * c - xi * sn;
        kpe_s[2 * tid + 1] = xr * sn + xi * c;
    }
    __syncthreads();
    const float tot = red[0] + red[1] + red[2] + red[3];
    const float inv = rsqrtf(tot * (1.0f / KV_LORA) + EPSF);
    kvn_bf[(size_t)row * KV_LORA + tid]       = f2bf(v0 * inv * w[tid]);
    kvn_bf[(size_t)row * KV_LORA + 256 + tid] = f2bf(v1 * inv * w[256 + tid]);
    const int bb = row >> 11, t = row & 2047;
    const int hh = tid >> 4, dg = (tid & 15) * 4;
    u16x4 pk;
#pragma unroll
    for (int j = 0; j < 4; ++j) pk[j] = f2bf(kpe_s[dg + j]);
    *(u16x4*)&kbuf[(((size_t)hh * 2 + bb) * 2048 + t) * 192 + 128 + dg] = pk;
}

// ---------------------------------------------------------------------------
// MFMA flash attention v4: 512 blocks (2/CU for latency hiding) with
// complementary-qt co-residency. qt mapping makes co-resident pairs sum to 15
// under either plausible packing (consecutive linear IDs, or IDs 256 apart):
//   qt_base(x) = (x&1) ? 15-(x>>1) : (x>>1)   [consecutive x sum to 15]
//   qt = z ? 15-qt_base : qt_base             [same (x,y) across z sum to 15]
// Per block: 128 q-rows, 32 q/wave (2 groups of 16), 64-token K/V tiles;
// each K/V LDS fragment feeds 2 MFMAs. Mask VALU only on diagonal tiles.
// LDS 58KB -> 2 blocks/CU (116KB < 160KB).
// ---------------------------------------------------------------------------
__global__ __launch_bounds__(256, 2) void attn_mfma(const u16* __restrict__ qbf,
                                                    const u16* __restrict__ kbuf,
                                                    const u16* __restrict__ vT,
                                                    u16* __restrict__ att,
                                                    float scale) {
    __shared__ __attribute__((aligned(16))) u16 Ks[6 * 64 * 32];
    __shared__ __attribute__((aligned(16))) u16 Vs[2 * 128 * 32];
    __shared__ __attribute__((aligned(16))) u16 Ps[4][32 * 72];
    const int x = blockIdx.x;
    const int qt_base = (x & 1) ? (15 - (x >> 1)) : (x >> 1);
    const int qt = blockIdx.z ? (15 - qt_base) : qt_base;
    const int h = blockIdx.y, b = blockIdx.z;
    const int tid = threadIdx.x, wave = tid >> 6, lane = tid & 63;
    const int l15 = lane & 15, lg = lane >> 4;

    const u16* kb_base = kbuf + ((size_t)(h * 2 + b)) * 2048 * 192;
    const u16* vt_base = vT   + ((size_t)(h * 2 + b)) * 128 * 2048;

    // Q B-frags for this wave's 2 q-groups
    int qrow[2];
    bf16x8 qf[2][6];
#pragma unroll
    for (int g = 0; g < 2; ++g) {
        qrow[g] = qt * 128 + g * 64 + wave * 16 + l15;
        const size_t qoff = ((size_t)(b * SEQ + qrow[g])) * QROW + h * 192 + lg * 8;
#pragma unroll
        for (int s = 0; s < 6; ++s) qf[g][s] = *(const bf16x8*)&qbf[qoff + s * 32];
    }

    floatx4 oacc[2][8];
#pragma unroll
    for (int g = 0; g < 2; ++g)
#pragma unroll
        for (int v = 0; v < 8; ++v) oacc[g][v] = 0.f;
    float m_run[2] = {-1e30f, -1e30f}, l_run[2] = {0.f, 0.f};

    const int kt_max = 2 * qt + 1;
    for (int kt = 0; kt <= kt_max; ++kt) {
        const int t0 = kt * 64;
        __syncthreads();
        // stage K tile [64][192] -> Ks[s][t][32]; 6 calls per wave
#pragma unroll
        for (int i = 0; i < 6; ++i) {
            const int base = (wave * 6 + i) * 64;
            const int slot = base + lane;
            const int s = slot >> 8, r = slot & 255, tk = r >> 2, ch = r & 3;
            async_copy16(kb_base + ((size_t)(t0 + tk)) * 192 + s * 32 + ch * 8,
                         &Ks[base * 8]);
        }
        // stage V^T tile [128][64] -> Vs[s][v][32]; 4 calls per wave
#pragma unroll
        for (int i = 0; i < 4; ++i) {
            const int base = (wave * 4 + i) * 64;
            const int slot = base + lane;
            const int s = slot >> 9, r = slot & 511, v = r >> 2, ch = r & 3;
            async_copy16(vt_base + ((size_t)v) * 2048 + t0 + s * 32 + ch * 8,
                         &Vs[base * 8]);
        }
        __syncthreads();
        // S^T[64t][16q] per group: share each K frag across both q-groups
        floatx4 sacc[2][4];
#pragma unroll
        for (int g = 0; g < 2; ++g)
#pragma unroll
            for (int mt = 0; mt < 4; ++mt) sacc[g][mt] = 0.f;
#pragma unroll
        for (int s = 0; s < 6; ++s) {
#pragma unroll
            for (int mt = 0; mt < 4; ++mt) {
                const bf16x8 kf = *(const bf16x8*)&Ks[(s * 64 + mt * 16 + l15) * 32 + lg * 8];
#pragma unroll
                for (int g = 0; g < 2; ++g)
                    sacc[g][mt] = __builtin_amdgcn_mfma_f32_16x16x32_bf16(
                        kf, qf[g][s], sacc[g][mt], 0, 0, 0);
            }
        }
        // online softmax per q-col
        float alpha[2];
#pragma unroll
        for (int g = 0; g < 2; ++g) {
            const bool full = (t0 + 63) <= (qt * 128 + g * 64 + wave * 16);
            float p[16];
            float tmax = -1e30f;
#pragma unroll
            for (int mt = 0; mt < 4; ++mt)
#pragma unroll
                for (int r = 0; r < 4; ++r) {
                    float v = sacc[g][mt][r] * scale;
                    if (!full) {
                        const int tglob = t0 + mt * 16 + lg * 4 + r;
                        v = (tglob <= qrow[g]) ? v : -1e30f;
                    }
                    p[mt * 4 + r] = v;
                    tmax = fmaxf(tmax, v);
                }
            tmax = fmaxf(tmax, __shfl_xor(tmax, 16));
            tmax = fmaxf(tmax, __shfl_xor(tmax, 32));
            const float mnew = fmaxf(m_run[g], tmax);
            alpha[g] = __expf(m_run[g] - mnew);
            m_run[g] = mnew;
            float rsum = 0.f;
#pragma unroll
            for (int k = 0; k < 16; ++k) { p[k] = __expf(p[k] - mnew); rsum += p[k]; }
            rsum += __shfl_xor(rsum, 16);
            rsum += __shfl_xor(rsum, 32);
            l_run[g] = l_run[g] * alpha[g] + rsum;
#pragma unroll
            for (int mt = 0; mt < 4; ++mt) {
                u16x4 pk;
#pragma unroll
                for (int r = 0; r < 4; ++r) pk[r] = f2bf(p[mt * 4 + r]);
                *(u16x4*)&Ps[wave][(g * 16 + l15) * 72 + mt * 16 + lg * 4] = pk;
            }
        }
        // rescale O by alpha per q-row
#pragma unroll
        for (int g = 0; g < 2; ++g) {
            float af[4];
#pragma unroll
            for (int r = 0; r < 4; ++r) af[r] = __shfl(alpha[g], lg * 4 + r);
#pragma unroll
            for (int vt = 0; vt < 8; ++vt)
#pragma unroll
                for (int r = 0; r < 4; ++r) oacc[g][vt][r] *= af[r];
        }
        // O[g][16q][128v] += P @ V
#pragma unroll
        for (int s = 0; s < 2; ++s) {
            bf16x8 pf[2];
#pragma unroll
            for (int g = 0; g < 2; ++g)
                pf[g] = *(const bf16x8*)&Ps[wave][(g * 16 + l15) * 72 + s * 32 + lg * 8];
#pragma unroll
            for (int vt = 0; vt < 8; ++vt) {
                const bf16x8 vf = *(const bf16x8*)&Vs[(s * 128 + vt * 16 + l15) * 32 + lg * 8];
#pragma unroll
                for (int g = 0; g < 2; ++g)
                    oacc[g][vt] = __builtin_amdgcn_mfma_f32_16x16x32_bf16(
                        pf[g], vf, oacc[g][vt], 0, 0, 0);
            }
        }
    }
    // epilogue: divide by l, store bf16
#pragma unroll
    for (int g = 0; g < 2; ++g) {
        float lf[4];
#pragma unroll
        for (int r = 0; r < 4; ++r) lf[r] = 1.0f / __shfl(l_run[g], lg * 4 + r);
#pragma unroll
        for (int vt = 0; vt < 8; ++vt)
#pragma unroll
            for (int r = 0; r < 4; ++r) {
                const int orow = b * SEQ + qt * 128 + g * 64 + wave * 16 + lg * 4 + r;
                att[(size_t)orow * 2048 + h * 128 + vt * 16 + l15] =
                    f2bf(oacc[g][vt][r] * lf[r]);
            }
    }
}

// ---------------------------------------------------------------------------
extern "C" void kernel_launch(void* const* d_in, const int* in_sizes, int n_in,
                              void* d_out, int out_size, void* d_ws, size_t ws_size,
                              hipStream_t stream) {
    const float* x     = (const float*)d_in[0];
    const float* wq    = (const float*)d_in[1];
    const float* wkv_a = (const float*)d_in[2];
    const float* knw   = (const float*)d_in[3];
    const float* wkv_b = (const float*)d_in[4];
    const float* wo    = (const float*)d_in[5];
    const float* fcos  = (const float*)d_in[6];
    const float* fsin  = (const float*)d_in[7];
    float* out = (float*)d_out;

    char* w = (char*)d_ws;
    u16*   x_bf    = (u16*)w;  w += (size_t)NTOK * 2048 * 2;
    u16*   wq_bf   = (u16*)w;  w += (size_t)QROW * 2048 * 2;
    u16*   wkva_bf = (u16*)w;  w += (size_t)640 * 2048 * 2;
    u16*   wkvb_bf = (u16*)w;  w += (size_t)KVBROW * KV_LORA * 2;
    u16*   wo_bf   = (u16*)w;  w += (size_t)2048 * 2048 * 2;
    u16*   q_bf    = (u16*)w;  w += (size_t)NTOK * QROW * 2;
    float* kv_raw  = (float*)w; w += (size_t)NTOK * 640 * 4;
    u16*   kvn_bf  = (u16*)w;  w += (size_t)NTOK * KV_LORA * 2;
    u16*   kbuf    = (u16*)w;  w += (size_t)NH * NB * SEQ * 192 * 2;
    u16*   vT      = (u16*)w;  w += (size_t)NH * NB * 128 * SEQ * 2;
    u16*   att_bf  = (u16*)w;  w += (size_t)NTOK * 2048 * 2;

    const double mm = 0.1 * 1.0 * log(40.0) + 1.0;
    const float scale = (float)((1.0 / sqrt((double)D_QK)) * mm * mm);

    dim3 blk(256);
    cast_all<<<dim3(21760), blk, 0, stream>>>(x, wq, wkv_a, wkv_b, wo,
                                              x_bf, wq_bf, wkva_bf, wkvb_bf, wo_bf);
    gemm_mfma<1><<<dim3(QROW / 128, NTOK / 128), blk, 0, stream>>>(
        x_bf, wq_bf, q_bf, nullptr, nullptr, NTOK, QROW, 2048);
    gemm_mfma<0><<<dim3(640 / 128, NTOK / 128), blk, 0, stream>>>(
        x_bf, wkva_bf, kv_raw, nullptr, nullptr, NTOK, 640, 2048);
    kv_fix<<<dim3(NTOK), blk, 0, stream>>>(kv_raw, knw, fcos, fsin, kvn_bf, kbuf);
    gemm_mfma<2><<<dim3(KVBROW / 128, NTOK / 128), blk, 0, stream>>>(
        kvn_bf, wkvb_bf, nullptr, kbuf, vT, NTOK, KVBROW, KV_LORA);
    attn_mfma<<<dim3(SEQ / 128, NH, NB), blk, 0, stream>>>(q_bf, kbuf, vT, att_bf, scale);
    gemm_mfma<0><<<dim3(2048 / 128, NTOK / 128), blk, 0, stream>>>(
        att_bf, wo_bf, out, nullptr, nullptr, NTOK, 2048, 2048);
}